// Round 3
// baseline (3837.464 us; speedup 1.0000x reference)
//
#include <hip/hip_runtime.h>
#include <hip/hip_bf16.h>
#include <stdint.h>

// ---------------------------------------------------------------------------
// M6_GraphBiLSTM: conv1 -> conv2 -> GAT x2 -> BiLSTM x2 -> MHA -> pool -> FC
// Round 3 == Round 2 resubmit (round 2 hit GPUAcquisitionTimeout, never ran).
// Workspace 223MB (round-1 failure attributed to ws_size < 425MB plan).
// GAT projection fused into GAT kernel (MFMA per block), gat2 in-place,
// LSTM directions serialized on one gate buffer.
// Shapes: B=256, C=16, T=256, TC=128, H=128, HEADS=4, D=32, E=256
// ---------------------------------------------------------------------------

typedef __attribute__((ext_vector_type(8))) short bh8;    // 8 x bf16 (4 VGPR)
typedef __attribute__((ext_vector_type(4))) float f32x4;  // MFMA accumulator

__device__ __forceinline__ float bfu2f(unsigned short u) {
  union { unsigned u; float f; } x; x.u = ((unsigned)u) << 16; return x.f;
}
__device__ __forceinline__ unsigned short f2bfu(float f) {
  __hip_bfloat16 h = __float2bfloat16(f);
  return *reinterpret_cast<unsigned short*>(&h);
}
__device__ __forceinline__ float geluf(float v) {
  return 0.5f * v * (1.f + erff(v * 0.70710678118f));
}
__device__ __forceinline__ float sigmoidf_(float x) { return 1.f / (1.f + __expf(-x)); }
__device__ __forceinline__ float tanh_(float x) {
  x = fminf(fmaxf(x, -30.f), 30.f);
  float e = __expf(2.f * x);
  return (e - 1.f) / (e + 1.f);
}

// async global->LDS, 16B per lane; LDS dest = wave-uniform base + lane*16
__device__ __forceinline__ void g2l16(const void* g, void* l) {
  __builtin_amdgcn_global_load_lds(
      (const __attribute__((address_space(1))) unsigned int*)g,
      (__attribute__((address_space(3))) unsigned int*)l, 16, 0, 0);
}

// ---------------------------------------------------------------------------
// Weight prep
// ---------------------------------------------------------------------------
__global__ __launch_bounds__(256) void cvt_bf16_k(const float* __restrict__ s,
                                                  __hip_bfloat16* __restrict__ d, int n) {
  int i = blockIdx.x * 256 + threadIdx.x;
  if (i < n) d[i] = __float2bfloat16(s[i]);
}

// d[c*R + r] = s[r*C + c]  (produces (C,R) = s^T as bf16)
__global__ __launch_bounds__(256) void tr_bf16_k(const float* __restrict__ s,
                                                 __hip_bfloat16* __restrict__ d, int R, int C) {
  int i = blockIdx.x * 256 + threadIdx.x;
  if (i < R * C) {
    int r = i / C, c = i % C;
    d[c * R + r] = __float2bfloat16(s[i]);
  }
}

// ---------------------------------------------------------------------------
// conv1 (k=7, pad 3) + BN + GELU.  x:(4096,256) f32 -> c1:(4096,32,256) bf16
// ---------------------------------------------------------------------------
__global__ __launch_bounds__(256)
void conv1_k(const float* __restrict__ x, const float* __restrict__ w,
             const float* __restrict__ b, const float* __restrict__ g,
             const float* __restrict__ bb, __hip_bfloat16* __restrict__ c1) {
  __shared__ float xs[264];
  const int nn = blockIdx.x, t = threadIdx.x;
  xs[3 + t] = x[nn * 256 + t];
  if (t < 3) { xs[t] = 0.f; xs[259 + t] = 0.f; }
  __syncthreads();
  for (int oc = 0; oc < 32; oc++) {
    float acc = 0.f;
#pragma unroll
    for (int k = 0; k < 7; k++) acc += xs[t + k] * w[oc * 7 + k];
    float v = (acc + b[oc]) * g[oc] + bb[oc];
    c1[(nn * 32 + oc) * 256 + t] = __float2bfloat16(geluf(v));
  }
}

// ---------------------------------------------------------------------------
// conv2 (k=5, s=2, pad 2) + BN + GELU.  c1 bf16 -> g0 bf16 in GAT layout:
// g0[((b*128+to)*16 + c)*64 + oc],  nn = b*16+c
// ---------------------------------------------------------------------------
__global__ __launch_bounds__(256)
void conv2_k(const __hip_bfloat16* __restrict__ c1, const float* __restrict__ w2,
             const float* __restrict__ b2, const float* __restrict__ g2,
             const float* __restrict__ bb2, __hip_bfloat16* __restrict__ g0) {
  __shared__ float ins[32 * 264];   // [ic][264], data at +2, zeros at 0,1,258,259
  __shared__ float wsh[64 * 161];   // [oc][161] padded (161 % 32 == 1)
  const int nn = blockIdx.x, tid = threadIdx.x;
  for (int idx = tid; idx < 64 * 160; idx += 256)
    wsh[(idx / 160) * 161 + idx % 160] = w2[idx];
  for (int idx = tid; idx < 32 * 4; idx += 256) {
    int ic = idx >> 2, p = idx & 3;
    ins[ic * 264 + (p < 2 ? p : 256 + p)] = 0.f;
  }
  for (int idx = tid; idx < 32 * 256; idx += 256) {
    int ic = idx >> 8, xq = idx & 255;
    ins[ic * 264 + 2 + xq] = __bfloat162float(c1[(nn * 32 + ic) * 256 + xq]);
  }
  __syncthreads();
  const int oc = tid & 63, tq = tid >> 6;
  float acc[32];
#pragma unroll
  for (int jj = 0; jj < 32; jj++) acc[jj] = 0.f;
  for (int ic = 0; ic < 32; ic++) {
    float wk0 = wsh[oc * 161 + ic * 5 + 0], wk1 = wsh[oc * 161 + ic * 5 + 1];
    float wk2 = wsh[oc * 161 + ic * 5 + 2], wk3 = wsh[oc * 161 + ic * 5 + 3];
    float wk4 = wsh[oc * 161 + ic * 5 + 4];
    const float* row = &ins[ic * 264];
#pragma unroll
    for (int jj = 0; jj < 32; jj++) {
      const int xb = tq * 64 + 2 * jj;  // = 2*to
      acc[jj] += row[xb] * wk0 + row[xb + 1] * wk1 + row[xb + 2] * wk2 +
                 row[xb + 3] * wk3 + row[xb + 4] * wk4;
    }
  }
  const int b = nn >> 4, c = nn & 15;
  const float gg = g2[oc], bbv = bb2[oc], bs = b2[oc];
#pragma unroll
  for (int jj = 0; jj < 32; jj++) {
    const int to = tq * 32 + jj;
    float v = (acc[jj] + bs) * gg + bbv;
    g0[((long)(b * 128 + to) * 16 + c) * 64 + oc] = __float2bfloat16(geluf(v));
  }
}

// ---------------------------------------------------------------------------
// bf16 MFMA GEMM:  C(M,N) = A(M,K) @ B(N,K)^T  (+bias[N]), m97 structure.
// 128x128 tile, BK=32, 4 waves (2x2), 16x16x32 MFMA, global_load_lds staging.
// ---------------------------------------------------------------------------
template <bool OUT_BF16>
__global__ __launch_bounds__(256)
void gemm_bt(const __hip_bfloat16* __restrict__ A, const __hip_bfloat16* __restrict__ Bm,
             void* __restrict__ Cout, const float* __restrict__ bias,
             int M, int N, int K) {
  __shared__ __align__(16) __hip_bfloat16 sA[128 * 32];
  __shared__ __align__(16) __hip_bfloat16 sB[128 * 32];
  const int tid = threadIdx.x;
  const int lane = tid & 63, wv = tid >> 6;
  const int wr = wv >> 1, wc = wv & 1;
  const long m0 = (long)blockIdx.y * 128;
  const long n0 = (long)blockIdx.x * 128;
  // staging: 512 16B-chunks per matrix; this thread owns 2 (q=0,1)
  const int sa0 = wv * 128 + lane, sa1 = wv * 128 + 64 + lane;
  const int ra0 = sa0 >> 2, ca0 = sa0 & 3;
  const int ra1 = sa1 >> 2, ca1 = sa1 & 3;
  const __hip_bfloat16* a0 = A + (m0 + ra0) * K + ca0 * 8;
  const __hip_bfloat16* a1 = A + (m0 + ra1) * K + ca1 * 8;
  const __hip_bfloat16* b0 = Bm + (n0 + ra0) * K + ca0 * 8;
  const __hip_bfloat16* b1 = Bm + (n0 + ra1) * K + ca1 * 8;
  char* lA0 = (char*)sA + wv * 2048;
  char* lA1 = (char*)sA + wv * 2048 + 1024;
  char* lB0 = (char*)sB + wv * 2048;
  char* lB1 = (char*)sB + wv * 2048 + 1024;
  f32x4 acc[4][4] = {};
  const int rfA = wr * 64 + (lane & 15);
  const int rfB = wc * 64 + (lane & 15);
  const int kf = (lane >> 4) * 8;
  for (int kt = 0; kt < K; kt += 32) {
    __syncthreads();
    g2l16(a0 + kt, lA0);
    g2l16(a1 + kt, lA1);
    g2l16(b0 + kt, lB0);
    g2l16(b1 + kt, lB1);
    __syncthreads();
    bh8 af[4], bf[4];
#pragma unroll
    for (int m = 0; m < 4; m++) af[m] = *(const bh8*)(sA + (rfA + m * 16) * 32 + kf);
#pragma unroll
    for (int n = 0; n < 4; n++) bf[n] = *(const bh8*)(sB + (rfB + n * 16) * 32 + kf);
#pragma unroll
    for (int m = 0; m < 4; m++)
#pragma unroll
      for (int n = 0; n < 4; n++)
        acc[m][n] = __builtin_amdgcn_mfma_f32_16x16x32_bf16(af[m], bf[n], acc[m][n], 0, 0, 0);
  }
#pragma unroll
  for (int n = 0; n < 4; n++) {
    const long col = n0 + wc * 64 + n * 16 + (lane & 15);
    const float bv = bias ? bias[col] : 0.f;
#pragma unroll
    for (int m = 0; m < 4; m++) {
      const long row0 = m0 + wr * 64 + m * 16 + ((lane >> 4) * 4);
#pragma unroll
      for (int r = 0; r < 4; r++) {
        float v = acc[m][n][r] + bv;
        if (OUT_BF16)
          ((__hip_bfloat16*)Cout)[(row0 + r) * N + col] = __float2bfloat16(v);
        else
          ((float*)Cout)[(row0 + r) * N + col] = v;
      }
    }
  }
}

// ---------------------------------------------------------------------------
// Fused GAT layer (per n of 32768): h = h_in(16,K) @ W(K,128) via MFMA,
// then GAT attention, ReLU, LayerNorm(128). out[(n*16+i)*128+f] bf16.
// wt is W^T (128,K) bf16 (L2-resident, read directly).  In-place safe:
// all global reads of hin happen before the first __syncthreads; writes last.
// ---------------------------------------------------------------------------
template <int K>
__global__ __launch_bounds__(128)
void gat_fused_k(const __hip_bfloat16* __restrict__ hin,
                 const __hip_bfloat16* __restrict__ wt,
                 const float* __restrict__ asrc, const float* __restrict__ adst,
                 const float* __restrict__ adj, const float* __restrict__ lng,
                 const float* __restrict__ lnb, __hip_bfloat16* __restrict__ outp) {
  const long n = blockIdx.x;
  const int f = threadIdx.x;          // 0..127, f = head*32 + d
  const int lane = f & 63, wv = f >> 6;
  const int head = f >> 5, d = f & 31;
  __shared__ float hs[16][132];       // projected h, f32 (+4 pad)
  __shared__ float adj_s[16][16];
  __shared__ float es_s[16][4], ed_s[16][4];
  __shared__ float a_s[16][16][4];
  __shared__ float red_s[2][16][2];
  // --- projection: wave wv computes cols wv*64..wv*64+63 of (16,128) ---
  const __hip_bfloat16* An = hin + n * 16 * K;
  const int ar = lane & 15, ak = (lane >> 4) * 8;
  f32x4 pacc[4] = {};
  for (int kt = 0; kt < K; kt += 32) {
    const bh8 af = *(const bh8*)(An + ar * K + kt + ak);
#pragma unroll
    for (int s = 0; s < 4; s++) {
      const bh8 bf = *(const bh8*)(wt + (wv * 64 + s * 16 + ar) * K + kt + ak);
      pacc[s] = __builtin_amdgcn_mfma_f32_16x16x32_bf16(af, bf, pacc[s], 0, 0, 0);
    }
  }
  for (int idx = f; idx < 256; idx += 128) adj_s[idx >> 4][idx & 15] = adj[idx];
#pragma unroll
  for (int s = 0; s < 4; s++)
#pragma unroll
    for (int r = 0; r < 4; r++)
      hs[(lane >> 4) * 4 + r][wv * 64 + s * 16 + ar] = pacc[s][r];
  __syncthreads();
  // --- attention (thread f owns feature f for all 16 channels) ---
  float hv[16];
#pragma unroll
  for (int c = 0; c < 16; c++) hv[c] = hs[c][f];
  const float as = asrc[head * 32 + d], ad = adst[head * 32 + d];
#pragma unroll
  for (int c = 0; c < 16; c++) {
    float e1 = hv[c] * as, e2 = hv[c] * ad;
#pragma unroll
    for (int m = 1; m < 32; m <<= 1) { e1 += __shfl_xor(e1, m); e2 += __shfl_xor(e2, m); }
    if (d == 0) { es_s[c][head] = e1; ed_s[c][head] = e2; }
  }
  __syncthreads();
  if (f < 64) {
    const int i = f >> 2, hd = f & 3;
    float ev[16], mx = -1e30f;
#pragma unroll
    for (int j = 0; j < 16; j++) {
      float e = es_s[i][hd] + ed_s[j][hd];
      e = (e > 0.f ? e : 0.2f * e) + adj_s[i][j];
      ev[j] = e; mx = fmaxf(mx, e);
    }
    float sm = 0.f;
#pragma unroll
    for (int j = 0; j < 16; j++) { ev[j] = __expf(ev[j] - mx); sm += ev[j]; }
    const float inv = 1.f / sm;
#pragma unroll
    for (int j = 0; j < 16; j++) a_s[i][j][hd] = ev[j] * inv;
  }
  __syncthreads();
  float o[16];
#pragma unroll
  for (int i = 0; i < 16; i++) {
    float acc = 0.f;
#pragma unroll
    for (int j = 0; j < 16; j++) acc += a_s[i][j][head] * hv[j];
    acc = fmaxf(acc, 0.f);   // ReLU
    o[i] = acc;
    float s = acc, ss = acc * acc;
#pragma unroll
    for (int m = 1; m < 64; m <<= 1) { s += __shfl_xor(s, m); ss += __shfl_xor(ss, m); }
    if (lane == 0) { red_s[wv][i][0] = s; red_s[wv][i][1] = ss; }
  }
  __syncthreads();
  const float gw = lng[f], gb = lnb[f];
#pragma unroll
  for (int i = 0; i < 16; i++) {
    const float s = red_s[0][i][0] + red_s[1][i][0];
    const float ss = red_s[0][i][1] + red_s[1][i][1];
    const float mean = s * (1.f / 128.f);
    const float var = ss * (1.f / 128.f) - mean * mean;
    const float r = rsqrtf(var + 1e-5f);
    outp[(n * 16 + i) * 128 + f] = __float2bfloat16((o[i] - mean) * r * gw + gb);
  }
}

// ---------------------------------------------------------------------------
// BiLSTM recurrence, ONE direction. Gates (x@Wih^T, no bias) precomputed f32.
// One block = 4-batch chunk (64 blocks), 512 threads (thread = gate j),
// T=128 steps, Whh^T staged bf16 in LDS. out[b][t][colOff + j] bf16, stride 256.
// ---------------------------------------------------------------------------
__global__ __launch_bounds__(512)
void lstm_rec_k(const float* __restrict__ gates, const float* __restrict__ whh,
                const float* __restrict__ bih, const float* __restrict__ bhh,
                __hip_bfloat16* __restrict__ outp, const int dir, const int colOff) {
  const int chunk = blockIdx.x;
  const int tid = threadIdx.x;
  __shared__ __align__(16) __hip_bfloat16 whh_s[512 * 128];  // [k/4][j][k%4] packed
  __shared__ __align__(16) float h_s[4][128];
  __shared__ float g_s[4][512];
  for (int idx = tid; idx < 512 * 128; idx += 512) {
    const int j = idx >> 7, k = idx & 127;
    whh_s[((k >> 2) * 512 + j) * 4 + (k & 3)] = __float2bfloat16(whh[idx]);
  }
  (&h_s[0][0])[tid] = 0.f;
  const float bias = bih[tid] + bhh[tid];
  const int ub = tid >> 7, uj = tid & 127;  // cell-update mapping (b, h-unit)
  float c_st = 0.f;
  __syncthreads();
  for (int s = 0; s < 128; s++) {
    const int t = dir ? (127 - s) : s;
    const long gb = ((long)(chunk * 4) * 128 + t) * 512 + tid;
    float acc0 = bias + gates[gb];
    float acc1 = bias + gates[gb + 65536];
    float acc2 = bias + gates[gb + 2 * 65536];
    float acc3 = bias + gates[gb + 3 * 65536];
#pragma unroll
    for (int q = 0; q < 32; q++) {
      const ushort4 wq = *(const ushort4*)(whh_s + (q * 512 + tid) * 4);
      const float w0 = bfu2f(wq.x), w1 = bfu2f(wq.y), w2 = bfu2f(wq.z), w3 = bfu2f(wq.w);
      const float4 h0 = *(const float4*)(&h_s[0][q * 4]);
      const float4 h1 = *(const float4*)(&h_s[1][q * 4]);
      const float4 h2 = *(const float4*)(&h_s[2][q * 4]);
      const float4 h3 = *(const float4*)(&h_s[3][q * 4]);
      acc0 += h0.x * w0 + h0.y * w1 + h0.z * w2 + h0.w * w3;
      acc1 += h1.x * w0 + h1.y * w1 + h1.z * w2 + h1.w * w3;
      acc2 += h2.x * w0 + h2.y * w1 + h2.z * w2 + h2.w * w3;
      acc3 += h3.x * w0 + h3.y * w1 + h3.z * w2 + h3.w * w3;
    }
    g_s[0][tid] = acc0; g_s[1][tid] = acc1; g_s[2][tid] = acc2; g_s[3][tid] = acc3;
    __syncthreads();
    {
      const float gi = sigmoidf_(g_s[ub][uj]);
      const float gf = sigmoidf_(g_s[ub][uj + 128]);
      const float gg = tanh_(g_s[ub][uj + 256]);
      const float go = sigmoidf_(g_s[ub][uj + 384]);
      const float c = gf * c_st + gi * gg;
      c_st = c;
      const float hh = go * tanh_(c);
      h_s[ub][uj] = hh;
      outp[((long)(chunk * 4 + ub) * 128 + t) * 256 + colOff + uj] = __float2bfloat16(hh);
    }
    __syncthreads();
  }
}

// ---------------------------------------------------------------------------
// MHA attention core: per (b, head) block. qkv bf16 (32768,768) -> ao bf16
// ---------------------------------------------------------------------------
#define DOT8T(Q, O, KV)                                                        \
  (Q[(O) + 0] * bfu2f((unsigned short)(KV)[0]) +                               \
   Q[(O) + 1] * bfu2f((unsigned short)(KV)[1]) +                               \
   Q[(O) + 2] * bfu2f((unsigned short)(KV)[2]) +                               \
   Q[(O) + 3] * bfu2f((unsigned short)(KV)[3]) +                               \
   Q[(O) + 4] * bfu2f((unsigned short)(KV)[4]) +                               \
   Q[(O) + 5] * bfu2f((unsigned short)(KV)[5]) +                               \
   Q[(O) + 6] * bfu2f((unsigned short)(KV)[6]) +                               \
   Q[(O) + 7] * bfu2f((unsigned short)(KV)[7]))

__global__ __launch_bounds__(256)
void mha_k(const __hip_bfloat16* __restrict__ qkv, __hip_bfloat16* __restrict__ ao) {
  const int bh = blockIdx.x;
  const int b = bh >> 2, hd = bh & 3;
  const int tid = threadIdx.x;
  __shared__ __align__(16) __hip_bfloat16 ks[128 * 68];
  __shared__ __align__(16) __hip_bfloat16 vs[128 * 68];
  __shared__ __align__(16) char xreg[33792];  // q [128][68] bf16, then P [128][132] bf16
  __shared__ float mx_s[2][128], sm_s[2][128];
  const long base = (long)b * 128 * 768 + hd * 64;
  for (int idx = tid; idx < 3072; idx += 256) {
    const int mm = idx >> 10, cc = idx & 1023;
    const int t = cc >> 3, c8 = cc & 7;
    const bh8 val = *(const bh8*)(qkv + base + (long)t * 768 + mm * 256 + c8 * 8);
    __hip_bfloat16* dst = (mm == 0) ? (__hip_bfloat16*)xreg : (mm == 1 ? ks : vs);
    *(bh8*)(dst + t * 68 + c8 * 8) = val;
  }
  __syncthreads();
  const int i = tid & 127;
  const int jh = tid >> 7;
  float qf[64];
#pragma unroll
  for (int kk = 0; kk < 8; kk++) {
    const bh8 v8 = *(const bh8*)((const __hip_bfloat16*)xreg + i * 68 + kk * 8);
#pragma unroll
    for (int e = 0; e < 8; e++) qf[kk * 8 + e] = bfu2f((unsigned short)v8[e]);
  }
  float s[64];
#pragma unroll
  for (int jo = 0; jo < 64; jo++) {
    const int j = jh * 64 + jo;
    float acc = 0.f;
#pragma unroll
    for (int kk = 0; kk < 8; kk++) {
      const bh8 kv = *(const bh8*)(ks + j * 68 + kk * 8);
      acc += DOT8T(qf, kk * 8, kv);
    }
    s[jo] = acc * 0.125f;
  }
  float mx = -1e30f;
#pragma unroll
  for (int jo = 0; jo < 64; jo++) mx = fmaxf(mx, s[jo]);
  mx_s[jh][i] = mx;
  __syncthreads();
  const float m = fmaxf(mx_s[0][i], mx_s[1][i]);
  float sum = 0.f;
#pragma unroll
  for (int jo = 0; jo < 64; jo++) { s[jo] = __expf(s[jo] - m); sum += s[jo]; }
  sm_s[jh][i] = sum;
  __syncthreads();
  const float inv = 1.f / (sm_s[0][i] + sm_s[1][i]);
  __hip_bfloat16* P = (__hip_bfloat16*)xreg;  // q region is dead now (qf loaded
  // before the mx_s barrier, so every thread is past its q reads)
#pragma unroll
  for (int jo = 0; jo < 64; jo += 2) {
    const unsigned u = (unsigned)f2bfu(s[jo] * inv) | ((unsigned)f2bfu(s[jo + 1] * inv) << 16);
    *(unsigned*)(P + i * 132 + jh * 64 + jo) = u;
  }
  __syncthreads();
  const int dh = jh;
  float acc[32];
#pragma unroll
  for (int e = 0; e < 32; e++) acc[e] = 0.f;
  for (int j = 0; j < 128; j++) {
    const float p = bfu2f(*(const unsigned short*)(P + i * 132 + j));
#pragma unroll
    for (int kk = 0; kk < 4; kk++) {
      const bh8 vv = *(const bh8*)(vs + j * 68 + dh * 32 + kk * 8);
      acc[kk * 8 + 0] += p * bfu2f((unsigned short)vv[0]);
      acc[kk * 8 + 1] += p * bfu2f((unsigned short)vv[1]);
      acc[kk * 8 + 2] += p * bfu2f((unsigned short)vv[2]);
      acc[kk * 8 + 3] += p * bfu2f((unsigned short)vv[3]);
      acc[kk * 8 + 4] += p * bfu2f((unsigned short)vv[4]);
      acc[kk * 8 + 5] += p * bfu2f((unsigned short)vv[5]);
      acc[kk * 8 + 6] += p * bfu2f((unsigned short)vv[6]);
      acc[kk * 8 + 7] += p * bfu2f((unsigned short)vv[7]);
    }
  }
  const long ob = ((long)b * 128 + i) * 256 + hd * 64 + dh * 32;
#pragma unroll
  for (int kk = 0; kk < 16; kk++) {
    const unsigned u = (unsigned)f2bfu(acc[2 * kk]) | ((unsigned)f2bfu(acc[2 * kk + 1]) << 16);
    *(unsigned*)(ao + ob + kk * 2) = u;
  }
}

// ---------------------------------------------------------------------------
// residual + LayerNorm(256):  att = LN(proj + out1)
// ---------------------------------------------------------------------------
__global__ __launch_bounds__(256)
void resid_ln_k(const float* __restrict__ proj, const __hip_bfloat16* __restrict__ o,
                const float* __restrict__ g, const float* __restrict__ bb,
                float* __restrict__ att) {
  const long m = blockIdx.x;
  const int t = threadIdx.x;
  const float v = proj[m * 256 + t] + __bfloat162float(o[m * 256 + t]);
  float sv = v, ssv = v * v;
#pragma unroll
  for (int mm = 1; mm < 64; mm <<= 1) { sv += __shfl_xor(sv, mm); ssv += __shfl_xor(ssv, mm); }
  __shared__ float red[4][2];
  const int lane = t & 63, wv = t >> 6;
  if (lane == 0) { red[wv][0] = sv; red[wv][1] = ssv; }
  __syncthreads();
  const float S = red[0][0] + red[1][0] + red[2][0] + red[3][0];
  const float SS = red[0][1] + red[1][1] + red[2][1] + red[3][1];
  const float mu = S * (1.f / 256.f);
  const float rr = rsqrtf(SS * (1.f / 256.f) - mu * mu + 1e-5f);
  att[m * 256 + t] = (v - mu) * rr * g[t] + bb[t];
}

// ---------------------------------------------------------------------------
// pooling (mean+max over t) -> LN(512) -> fc1+relu -> fc2 -> d_out[b]
// ---------------------------------------------------------------------------
__global__ __launch_bounds__(256)
void pool_k(const float* __restrict__ att, const float* __restrict__ png,
            const float* __restrict__ pnb, const float* __restrict__ f1w,
            const float* __restrict__ f1b, const float* __restrict__ f2w,
            const float* __restrict__ f2b, float* __restrict__ outp) {
  const int b = blockIdx.x, e = threadIdx.x;
  float sum = 0.f, mx = -1e30f;
  for (int t = 0; t < 128; t++) {
    const float v = att[((long)b * 128 + t) * 256 + e];
    sum += v; mx = fmaxf(mx, v);
  }
  const float a0 = sum * (1.f / 128.f), a1 = mx;
  float sv = a0 + a1, ssv = a0 * a0 + a1 * a1;
#pragma unroll
  for (int mm = 1; mm < 64; mm <<= 1) { sv += __shfl_xor(sv, mm); ssv += __shfl_xor(ssv, mm); }
  __shared__ float red[4][2];
  __shared__ float y[512];
  __shared__ float z[128];
  const int lane = e & 63, wv = e >> 6;
  if (lane == 0) { red[wv][0] = sv; red[wv][1] = ssv; }
  __syncthreads();
  const float S = red[0][0] + red[1][0] + red[2][0] + red[3][0];
  const float SS = red[0][1] + red[1][1] + red[2][1] + red[3][1];
  const float mu = S * (1.f / 512.f);
  const float rr = rsqrtf(SS * (1.f / 512.f) - mu * mu + 1e-5f);
  y[e] = (a0 - mu) * rr * png[e] + pnb[e];
  y[256 + e] = (a1 - mu) * rr * png[256 + e] + pnb[256 + e];
  __syncthreads();
  if (e < 128) {
    float a = f1b[e];
    for (int k = 0; k < 512; k++) a += y[k] * f1w[e * 512 + k];
    z[e] = fmaxf(a, 0.f);
  }
  __syncthreads();
  if (e < 64) {
    float p = z[e] * f2w[e] + z[e + 64] * f2w[e + 64];
#pragma unroll
    for (int mm = 1; mm < 64; mm <<= 1) p += __shfl_xor(p, mm);
    if (e == 0) outp[b] = p + f2b[0];
  }
}

// ---------------------------------------------------------------------------
// Host orchestration
// ---------------------------------------------------------------------------
extern "C" void kernel_launch(void* const* d_in, const int* in_sizes, int n_in,
                              void* d_out, int out_size, void* d_ws, size_t ws_size,
                              hipStream_t stream) {
  (void)in_sizes; (void)n_in; (void)out_size; (void)ws_size;
  const float* x      = (const float*)d_in[0];
  const float* c1w    = (const float*)d_in[1];
  const float* c1b    = (const float*)d_in[2];
  const float* bn1g   = (const float*)d_in[3];
  const float* bn1b   = (const float*)d_in[4];
  const float* c2w    = (const float*)d_in[5];
  const float* c2b    = (const float*)d_in[6];
  const float* bn2g   = (const float*)d_in[7];
  const float* bn2b   = (const float*)d_in[8];
  const float* g1W    = (const float*)d_in[9];
  const float* g1asrc = (const float*)d_in[10];
  const float* g1adst = (const float*)d_in[11];
  const float* g1adj  = (const float*)d_in[12];
  const float* n1g    = (const float*)d_in[13];
  const float* n1b    = (const float*)d_in[14];
  const float* g2W    = (const float*)d_in[15];
  const float* g2asrc = (const float*)d_in[16];
  const float* g2adst = (const float*)d_in[17];
  const float* g2adj  = (const float*)d_in[18];
  const float* n2g    = (const float*)d_in[19];
  const float* n2b    = (const float*)d_in[20];
  const float* l0fWih = (const float*)d_in[21];
  const float* l0fWhh = (const float*)d_in[22];
  const float* l0fbih = (const float*)d_in[23];
  const float* l0fbhh = (const float*)d_in[24];
  const float* l0rWih = (const float*)d_in[25];
  const float* l0rWhh = (const float*)d_in[26];
  const float* l0rbih = (const float*)d_in[27];
  const float* l0rbhh = (const float*)d_in[28];
  const float* l1fWih = (const float*)d_in[29];
  const float* l1fWhh = (const float*)d_in[30];
  const float* l1fbih = (const float*)d_in[31];
  const float* l1fbhh = (const float*)d_in[32];
  const float* l1rWih = (const float*)d_in[33];
  const float* l1rWhh = (const float*)d_in[34];
  const float* l1rbih = (const float*)d_in[35];
  const float* l1rbhh = (const float*)d_in[36];
  const float* wqkv   = (const float*)d_in[37];
  const float* bqkv   = (const float*)d_in[38];
  const float* wo     = (const float*)d_in[39];
  const float* bo     = (const float*)d_in[40];
  const float* ang    = (const float*)d_in[41];
  const float* anb    = (const float*)d_in[42];
  const float* png    = (const float*)d_in[43];
  const float* pnb    = (const float*)d_in[44];
  const float* f1w    = (const float*)d_in[45];
  const float* f1b    = (const float*)d_in[46];
  const float* f2w    = (const float*)d_in[47];
  const float* f2b    = (const float*)d_in[48];

  char* ws = (char*)d_ws;
  // Buffer overlay plan (total 223,395,840 B; lifetimes verified per stage):
  //  [0       , 67.1MB ) G0   (conv2 out) ........ then GAF (lstm gates f32)
  //  [67.1MB  , 134.2MB) C1   (conv1 out) ........ then low half of G1O,
  //                                               then OUT1 + QKV
  //  [67.1MB  , 201.3MB) G1O  (GAT out, (32768,2048) bf16, in-place gat2)
  //  [134.2MB , 218.1MB)      then AOb, PROJ, ATT
  //  [201.3MB , 218.1MB) OUT0 (lstm0 out)
  //  [218.1MB , 223.4MB) bf16 weights (persistent)
  auto G0   = (__hip_bfloat16*)(ws + 0L);
  auto C1   = (__hip_bfloat16*)(ws + 67108864L);
  auto G1O  = (__hip_bfloat16*)(ws + 67108864L);
  auto GAF  = (float*)(ws + 0L);
  auto OUT0 = (__hip_bfloat16*)(ws + 201326592L);
  auto OUT1 = (__hip_bfloat16*)(ws + 67108864L);
  auto QKV  = (__hip_bfloat16*)(ws + 83886080L);
  auto AOb  = (__hip_bfloat16*)(ws + 134217728L);
  auto PROJ = (float*)(ws + 150994944L);
  auto ATT  = (float*)(ws + 184549376L);
  char* WB  = ws + 218103808L;
  auto WG1T  = (__hip_bfloat16*)(WB + 0);        // (128,64)  = g1_W^T
  auto WG2T  = (__hip_bfloat16*)(WB + 16384);    // (128,128) = g2_W^T
  auto WI0F  = (__hip_bfloat16*)(WB + 49152);    // (512,2048)
  auto WI0R  = (__hip_bfloat16*)(WB + 2146304);
  auto WI1F  = (__hip_bfloat16*)(WB + 4243456);  // (512,256)
  auto WI1R  = (__hip_bfloat16*)(WB + 4505600);
  auto WQKVb = (__hip_bfloat16*)(WB + 4767744);  // (768,256)
  auto WOb   = (__hip_bfloat16*)(WB + 5160960);  // (256,256)

  // --- weight prep (bf16; Wih/wqkv/wo are already (N,K) = B^T layout) ---
  tr_bf16_k<<<32, 256, 0, stream>>>(g1W, WG1T, 64, 128);
  tr_bf16_k<<<64, 256, 0, stream>>>(g2W, WG2T, 128, 128);
  cvt_bf16_k<<<4096, 256, 0, stream>>>(l0fWih, WI0F, 1048576);
  cvt_bf16_k<<<4096, 256, 0, stream>>>(l0rWih, WI0R, 1048576);
  cvt_bf16_k<<<512, 256, 0, stream>>>(l1fWih, WI1F, 131072);
  cvt_bf16_k<<<512, 256, 0, stream>>>(l1rWih, WI1R, 131072);
  cvt_bf16_k<<<768, 256, 0, stream>>>(wqkv, WQKVb, 196608);
  cvt_bf16_k<<<256, 256, 0, stream>>>(wo, WOb, 65536);

  // --- pipeline ---
  conv1_k<<<4096, 256, 0, stream>>>(x, c1w, c1b, bn1g, bn1b, C1);
  conv2_k<<<4096, 256, 0, stream>>>(C1, c2w, c2b, bn2g, bn2b, G0);
  gat_fused_k<64><<<32768, 128, 0, stream>>>(G0, WG1T, g1asrc, g1adst, g1adj, n1g, n1b, G1O);
  gat_fused_k<128><<<32768, 128, 0, stream>>>(G1O, WG2T, g2asrc, g2adst, g2adj, n2g, n2b, G1O);
  // LSTM layer 0 (dirs serialized on one gate buffer)
  gemm_bt<false><<<dim3(4, 256), 256, 0, stream>>>(G1O, WI0F, GAF, nullptr, 32768, 512, 2048);
  lstm_rec_k<<<64, 512, 0, stream>>>(GAF, l0fWhh, l0fbih, l0fbhh, OUT0, 0, 0);
  gemm_bt<false><<<dim3(4, 256), 256, 0, stream>>>(G1O, WI0R, GAF, nullptr, 32768, 512, 2048);
  lstm_rec_k<<<64, 512, 0, stream>>>(GAF, l0rWhh, l0rbih, l0rbhh, OUT0, 1, 128);
  // LSTM layer 1
  gemm_bt<false><<<dim3(4, 256), 256, 0, stream>>>(OUT0, WI1F, GAF, nullptr, 32768, 512, 256);
  lstm_rec_k<<<64, 512, 0, stream>>>(GAF, l1fWhh, l1fbih, l1fbhh, OUT1, 0, 0);
  gemm_bt<false><<<dim3(4, 256), 256, 0, stream>>>(OUT0, WI1R, GAF, nullptr, 32768, 512, 256);
  lstm_rec_k<<<64, 512, 0, stream>>>(GAF, l1rWhh, l1rbih, l1rbhh, OUT1, 1, 128);
  // MHA block
  gemm_bt<true><<<dim3(6, 256), 256, 0, stream>>>(OUT1, WQKVb, QKV, bqkv, 32768, 768, 256);
  mha_k<<<1024, 256, 0, stream>>>(QKV, AOb);
  gemm_bt<false><<<dim3(2, 256), 256, 0, stream>>>(AOb, WOb, PROJ, bo, 32768, 256, 256);
  resid_ln_k<<<32768, 256, 0, stream>>>(PROJ, OUT1, ang, anb, ATT);
  pool_k<<<256, 256, 0, stream>>>(ATT, png, pnb, f1w, f1b, f2w, f2b, (float*)d_out);
}

// Round 5
// 2108.758 us; speedup vs baseline: 1.8198x; 1.8198x over previous
//
#include <hip/hip_runtime.h>
#include <hip/hip_bf16.h>
#include <stdint.h>

// ---------------------------------------------------------------------------
// M6_GraphBiLSTM: conv1 -> conv2 -> GAT x2 -> BiLSTM x2 -> MHA -> pool -> FC
// Round 5 == Round 4 resubmit (round 4 hit GPUAcquisitionTimeout, never ran).
// LSTM recurrence rebuilt around MFMA + register-resident Whh.
//   R3 profile: 4x lstm_rec_k @539us = 56% of runtime (latency-bound, occ 6%,
//   131KB of LDS weight reads per block per step). New lstm_mfma_k: weights
//   live in MFMA B-frags (64 VGPR/wave), h as bf16 A-frags in 4KB LDS,
//   128 blocks (chunk=2), ~8KB LDS total.
// Shapes: B=256, C=16, T=256, TC=128, H=128, HEADS=4, D=32, E=256
// ---------------------------------------------------------------------------

typedef __attribute__((ext_vector_type(8))) short bh8;    // 8 x bf16 (4 VGPR)
typedef __attribute__((ext_vector_type(4))) float f32x4;  // MFMA accumulator

__device__ __forceinline__ float bfu2f(unsigned short u) {
  union { unsigned u; float f; } x; x.u = ((unsigned)u) << 16; return x.f;
}
__device__ __forceinline__ unsigned short f2bfu(float f) {
  __hip_bfloat16 h = __float2bfloat16(f);
  return *reinterpret_cast<unsigned short*>(&h);
}
__device__ __forceinline__ float geluf(float v) {
  return 0.5f * v * (1.f + erff(v * 0.70710678118f));
}
__device__ __forceinline__ float sigmoidf_(float x) { return 1.f / (1.f + __expf(-x)); }
__device__ __forceinline__ float tanh_(float x) {
  x = fminf(fmaxf(x, -30.f), 30.f);
  float e = __expf(2.f * x);
  return (e - 1.f) / (e + 1.f);
}

// async global->LDS, 16B per lane; LDS dest = wave-uniform base + lane*16
__device__ __forceinline__ void g2l16(const void* g, void* l) {
  __builtin_amdgcn_global_load_lds(
      (const __attribute__((address_space(1))) unsigned int*)g,
      (__attribute__((address_space(3))) unsigned int*)l, 16, 0, 0);
}

// ---------------------------------------------------------------------------
// Weight prep
// ---------------------------------------------------------------------------
__global__ __launch_bounds__(256) void cvt_bf16_k(const float* __restrict__ s,
                                                  __hip_bfloat16* __restrict__ d, int n) {
  int i = blockIdx.x * 256 + threadIdx.x;
  if (i < n) d[i] = __float2bfloat16(s[i]);
}

// d[c*R + r] = s[r*C + c]  (produces (C,R) = s^T as bf16)
__global__ __launch_bounds__(256) void tr_bf16_k(const float* __restrict__ s,
                                                 __hip_bfloat16* __restrict__ d, int R, int C) {
  int i = blockIdx.x * 256 + threadIdx.x;
  if (i < R * C) {
    int r = i / C, c = i % C;
    d[c * R + r] = __float2bfloat16(s[i]);
  }
}

// ---------------------------------------------------------------------------
// conv1 (k=7, pad 3) + BN + GELU.  x:(4096,256) f32 -> c1:(4096,32,256) bf16
// ---------------------------------------------------------------------------
__global__ __launch_bounds__(256)
void conv1_k(const float* __restrict__ x, const float* __restrict__ w,
             const float* __restrict__ b, const float* __restrict__ g,
             const float* __restrict__ bb, __hip_bfloat16* __restrict__ c1) {
  __shared__ float xs[264];
  const int nn = blockIdx.x, t = threadIdx.x;
  xs[3 + t] = x[nn * 256 + t];
  if (t < 3) { xs[t] = 0.f; xs[259 + t] = 0.f; }
  __syncthreads();
  for (int oc = 0; oc < 32; oc++) {
    float acc = 0.f;
#pragma unroll
    for (int k = 0; k < 7; k++) acc += xs[t + k] * w[oc * 7 + k];
    float v = (acc + b[oc]) * g[oc] + bb[oc];
    c1[(nn * 32 + oc) * 256 + t] = __float2bfloat16(geluf(v));
  }
}

// ---------------------------------------------------------------------------
// conv2 (k=5, s=2, pad 2) + BN + GELU.  c1 bf16 -> g0 bf16 in GAT layout:
// g0[((b*128+to)*16 + c)*64 + oc],  nn = b*16+c
// ---------------------------------------------------------------------------
__global__ __launch_bounds__(256)
void conv2_k(const __hip_bfloat16* __restrict__ c1, const float* __restrict__ w2,
             const float* __restrict__ b2, const float* __restrict__ g2,
             const float* __restrict__ bb2, __hip_bfloat16* __restrict__ g0) {
  __shared__ float ins[32 * 264];   // [ic][264], data at +2, zeros at 0,1,258,259
  __shared__ float wsh[64 * 161];   // [oc][161] padded (161 % 32 == 1)
  const int nn = blockIdx.x, tid = threadIdx.x;
  for (int idx = tid; idx < 64 * 160; idx += 256)
    wsh[(idx / 160) * 161 + idx % 160] = w2[idx];
  for (int idx = tid; idx < 32 * 4; idx += 256) {
    int ic = idx >> 2, p = idx & 3;
    ins[ic * 264 + (p < 2 ? p : 256 + p)] = 0.f;
  }
  for (int idx = tid; idx < 32 * 256; idx += 256) {
    int ic = idx >> 8, xq = idx & 255;
    ins[ic * 264 + 2 + xq] = __bfloat162float(c1[(nn * 32 + ic) * 256 + xq]);
  }
  __syncthreads();
  const int oc = tid & 63, tq = tid >> 6;
  float acc[32];
#pragma unroll
  for (int jj = 0; jj < 32; jj++) acc[jj] = 0.f;
  for (int ic = 0; ic < 32; ic++) {
    float wk0 = wsh[oc * 161 + ic * 5 + 0], wk1 = wsh[oc * 161 + ic * 5 + 1];
    float wk2 = wsh[oc * 161 + ic * 5 + 2], wk3 = wsh[oc * 161 + ic * 5 + 3];
    float wk4 = wsh[oc * 161 + ic * 5 + 4];
    const float* row = &ins[ic * 264];
#pragma unroll
    for (int jj = 0; jj < 32; jj++) {
      const int xb = tq * 64 + 2 * jj;  // = 2*to
      acc[jj] += row[xb] * wk0 + row[xb + 1] * wk1 + row[xb + 2] * wk2 +
                 row[xb + 3] * wk3 + row[xb + 4] * wk4;
    }
  }
  const int b = nn >> 4, c = nn & 15;
  const float gg = g2[oc], bbv = bb2[oc], bs = b2[oc];
#pragma unroll
  for (int jj = 0; jj < 32; jj++) {
    const int to = tq * 32 + jj;
    float v = (acc[jj] + bs) * gg + bbv;
    g0[((long)(b * 128 + to) * 16 + c) * 64 + oc] = __float2bfloat16(geluf(v));
  }
}

// ---------------------------------------------------------------------------
// bf16 MFMA GEMM:  C(M,N) = A(M,K) @ B(N,K)^T  (+bias[N]), m97 structure.
// 128x128 tile, BK=32, 4 waves (2x2), 16x16x32 MFMA, global_load_lds staging.
// ---------------------------------------------------------------------------
template <bool OUT_BF16>
__global__ __launch_bounds__(256)
void gemm_bt(const __hip_bfloat16* __restrict__ A, const __hip_bfloat16* __restrict__ Bm,
             void* __restrict__ Cout, const float* __restrict__ bias,
             int M, int N, int K) {
  __shared__ __align__(16) __hip_bfloat16 sA[128 * 32];
  __shared__ __align__(16) __hip_bfloat16 sB[128 * 32];
  const int tid = threadIdx.x;
  const int lane = tid & 63, wv = tid >> 6;
  const int wr = wv >> 1, wc = wv & 1;
  const long m0 = (long)blockIdx.y * 128;
  const long n0 = (long)blockIdx.x * 128;
  // staging: 512 16B-chunks per matrix; this thread owns 2 (q=0,1)
  const int sa0 = wv * 128 + lane, sa1 = wv * 128 + 64 + lane;
  const int ra0 = sa0 >> 2, ca0 = sa0 & 3;
  const int ra1 = sa1 >> 2, ca1 = sa1 & 3;
  const __hip_bfloat16* a0 = A + (m0 + ra0) * K + ca0 * 8;
  const __hip_bfloat16* a1 = A + (m0 + ra1) * K + ca1 * 8;
  const __hip_bfloat16* b0 = Bm + (n0 + ra0) * K + ca0 * 8;
  const __hip_bfloat16* b1 = Bm + (n0 + ra1) * K + ca1 * 8;
  char* lA0 = (char*)sA + wv * 2048;
  char* lA1 = (char*)sA + wv * 2048 + 1024;
  char* lB0 = (char*)sB + wv * 2048;
  char* lB1 = (char*)sB + wv * 2048 + 1024;
  f32x4 acc[4][4] = {};
  const int rfA = wr * 64 + (lane & 15);
  const int rfB = wc * 64 + (lane & 15);
  const int kf = (lane >> 4) * 8;
  for (int kt = 0; kt < K; kt += 32) {
    __syncthreads();
    g2l16(a0 + kt, lA0);
    g2l16(a1 + kt, lA1);
    g2l16(b0 + kt, lB0);
    g2l16(b1 + kt, lB1);
    __syncthreads();
    bh8 af[4], bf[4];
#pragma unroll
    for (int m = 0; m < 4; m++) af[m] = *(const bh8*)(sA + (rfA + m * 16) * 32 + kf);
#pragma unroll
    for (int n = 0; n < 4; n++) bf[n] = *(const bh8*)(sB + (rfB + n * 16) * 32 + kf);
#pragma unroll
    for (int m = 0; m < 4; m++)
#pragma unroll
      for (int n = 0; n < 4; n++)
        acc[m][n] = __builtin_amdgcn_mfma_f32_16x16x32_bf16(af[m], bf[n], acc[m][n], 0, 0, 0);
  }
#pragma unroll
  for (int n = 0; n < 4; n++) {
    const long col = n0 + wc * 64 + n * 16 + (lane & 15);
    const float bv = bias ? bias[col] : 0.f;
#pragma unroll
    for (int m = 0; m < 4; m++) {
      const long row0 = m0 + wr * 64 + m * 16 + ((lane >> 4) * 4);
#pragma unroll
      for (int r = 0; r < 4; r++) {
        float v = acc[m][n][r] + bv;
        if (OUT_BF16)
          ((__hip_bfloat16*)Cout)[(row0 + r) * N + col] = __float2bfloat16(v);
        else
          ((float*)Cout)[(row0 + r) * N + col] = v;
      }
    }
  }
}

// ---------------------------------------------------------------------------
// Fused GAT layer (per n of 32768): h = h_in(16,K) @ W(K,128) via MFMA,
// then GAT attention, ReLU, LayerNorm(128). out[(n*16+i)*128+f] bf16.
// wt is W^T (128,K) bf16 (L2-resident, read directly).  In-place safe:
// all global reads of hin happen before the first __syncthreads; writes last.
// ---------------------------------------------------------------------------
template <int K>
__global__ __launch_bounds__(128)
void gat_fused_k(const __hip_bfloat16* __restrict__ hin,
                 const __hip_bfloat16* __restrict__ wt,
                 const float* __restrict__ asrc, const float* __restrict__ adst,
                 const float* __restrict__ adj, const float* __restrict__ lng,
                 const float* __restrict__ lnb, __hip_bfloat16* __restrict__ outp) {
  const long n = blockIdx.x;
  const int f = threadIdx.x;          // 0..127, f = head*32 + d
  const int lane = f & 63, wv = f >> 6;
  const int head = f >> 5, d = f & 31;
  __shared__ float hs[16][132];       // projected h, f32 (+4 pad)
  __shared__ float adj_s[16][16];
  __shared__ float es_s[16][4], ed_s[16][4];
  __shared__ float a_s[16][16][4];
  __shared__ float red_s[2][16][2];
  // --- projection: wave wv computes cols wv*64..wv*64+63 of (16,128) ---
  const __hip_bfloat16* An = hin + n * 16 * K;
  const int ar = lane & 15, ak = (lane >> 4) * 8;
  f32x4 pacc[4] = {};
  for (int kt = 0; kt < K; kt += 32) {
    const bh8 af = *(const bh8*)(An + ar * K + kt + ak);
#pragma unroll
    for (int s = 0; s < 4; s++) {
      const bh8 bf = *(const bh8*)(wt + (wv * 64 + s * 16 + ar) * K + kt + ak);
      pacc[s] = __builtin_amdgcn_mfma_f32_16x16x32_bf16(af, bf, pacc[s], 0, 0, 0);
    }
  }
  for (int idx = f; idx < 256; idx += 128) adj_s[idx >> 4][idx & 15] = adj[idx];
#pragma unroll
  for (int s = 0; s < 4; s++)
#pragma unroll
    for (int r = 0; r < 4; r++)
      hs[(lane >> 4) * 4 + r][wv * 64 + s * 16 + ar] = pacc[s][r];
  __syncthreads();
  // --- attention (thread f owns feature f for all 16 channels) ---
  float hv[16];
#pragma unroll
  for (int c = 0; c < 16; c++) hv[c] = hs[c][f];
  const float as = asrc[head * 32 + d], ad = adst[head * 32 + d];
#pragma unroll
  for (int c = 0; c < 16; c++) {
    float e1 = hv[c] * as, e2 = hv[c] * ad;
#pragma unroll
    for (int m = 1; m < 32; m <<= 1) { e1 += __shfl_xor(e1, m); e2 += __shfl_xor(e2, m); }
    if (d == 0) { es_s[c][head] = e1; ed_s[c][head] = e2; }
  }
  __syncthreads();
  if (f < 64) {
    const int i = f >> 2, hd = f & 3;
    float ev[16], mx = -1e30f;
#pragma unroll
    for (int j = 0; j < 16; j++) {
      float e = es_s[i][hd] + ed_s[j][hd];
      e = (e > 0.f ? e : 0.2f * e) + adj_s[i][j];
      ev[j] = e; mx = fmaxf(mx, e);
    }
    float sm = 0.f;
#pragma unroll
    for (int j = 0; j < 16; j++) { ev[j] = __expf(ev[j] - mx); sm += ev[j]; }
    const float inv = 1.f / sm;
#pragma unroll
    for (int j = 0; j < 16; j++) a_s[i][j][hd] = ev[j] * inv;
  }
  __syncthreads();
  float o[16];
#pragma unroll
  for (int i = 0; i < 16; i++) {
    float acc = 0.f;
#pragma unroll
    for (int j = 0; j < 16; j++) acc += a_s[i][j][head] * hv[j];
    acc = fmaxf(acc, 0.f);   // ReLU
    o[i] = acc;
    float s = acc, ss = acc * acc;
#pragma unroll
    for (int m = 1; m < 64; m <<= 1) { s += __shfl_xor(s, m); ss += __shfl_xor(ss, m); }
    if (lane == 0) { red_s[wv][i][0] = s; red_s[wv][i][1] = ss; }
  }
  __syncthreads();
  const float gw = lng[f], gb = lnb[f];
#pragma unroll
  for (int i = 0; i < 16; i++) {
    const float s = red_s[0][i][0] + red_s[1][i][0];
    const float ss = red_s[0][i][1] + red_s[1][i][1];
    const float mean = s * (1.f / 128.f);
    const float var = ss * (1.f / 128.f) - mean * mean;
    const float r = rsqrtf(var + 1e-5f);
    outp[(n * 16 + i) * 128 + f] = __float2bfloat16((o[i] - mean) * r * gw + gb);
  }
}

// ---------------------------------------------------------------------------
// BiLSTM recurrence via MFMA, ONE direction. Gates (x@Wih^T) precomputed f32.
// Grid: 128 blocks (chunk = 2 sequences), 512 threads = 8 waves.
// Wave w owns gate columns [w*64, w*64+64): Whh^T held in registers as 16
// MFMA B-frags (64 VGPR). h kept bf16 in LDS in A-frag layout [kt][hi][b][e]
// (lane-linear 1024B reads per k-tile, conflict-free). c state f32 in regs.
// Per step: issue x-gate loads -> 4 ds_read_b128 -> 16 MFMA -> g_lds ->
// barrier -> cell update (256 threads, 1 cell each) -> barrier.
// ---------------------------------------------------------------------------
__global__ __launch_bounds__(512)
void lstm_mfma_k(const float* __restrict__ gates, const float* __restrict__ whh,
                 const float* __restrict__ bih, const float* __restrict__ bhh,
                 __hip_bfloat16* __restrict__ outp, const int dir, const int colOff) {
  const int chunk = blockIdx.x;            // sequences 2*chunk, 2*chunk+1
  const int tid = threadIdx.x;
  const int lane = tid & 63, w = tid >> 6;
  const int cl = lane & 15, hi = lane >> 4;
  __shared__ __align__(16) __hip_bfloat16 h_frag[2048];  // [kt][hi][b][e]=[4][4][16][8]
  __shared__ float g_lds[2][520];                        // [batch][gate j]
  // zero h state (rows b>=2 stay zero forever -> harmless MFMA garbage rows)
  for (int idx = tid; idx < 1024; idx += 512) ((unsigned*)h_frag)[idx] = 0u;
  // B-frags: lane holds Whh^T[j = w*64+n*16+cl][k = kt*32+hi*8 .. +8] as bf16x8
  bh8 bfr[4][4];
#pragma unroll
  for (int n = 0; n < 4; n++)
#pragma unroll
    for (int kt = 0; kt < 4; kt++) {
      const float* wp = whh + (w * 64 + n * 16 + cl) * 128 + kt * 32 + hi * 8;
      const float4 lo = *(const float4*)wp;
      const float4 hv = *(const float4*)(wp + 4);
      bh8 r;
      r[0] = (short)f2bfu(lo.x); r[1] = (short)f2bfu(lo.y);
      r[2] = (short)f2bfu(lo.z); r[3] = (short)f2bfu(lo.w);
      r[4] = (short)f2bfu(hv.x); r[5] = (short)f2bfu(hv.y);
      r[6] = (short)f2bfu(hv.z); r[7] = (short)f2bfu(hv.w);
      bfr[n][kt] = r;
    }
  float bs[4];
#pragma unroll
  for (int n = 0; n < 4; n++)
    bs[n] = bih[w * 64 + n * 16 + cl] + bhh[w * 64 + n * 16 + cl];
  const int ub = tid >> 7, uj = tid & 127;  // cell mapping (batch, h-unit), tid<256
  float c_st = 0.f;
  __syncthreads();
  for (int s = 0; s < 128; s++) {
    const int t = dir ? (127 - s) : s;
    // x-gate inputs for this step (only hi==0 lanes consume; issue early)
    float gin[4][2];
    if (hi == 0) {
#pragma unroll
      for (int n = 0; n < 4; n++)
#pragma unroll
        for (int r = 0; r < 2; r++)
          gin[n][r] = gates[((long)(chunk * 2 + r) * 128 + t) * 512 + w * 64 + n * 16 + cl];
    }
    // A-frags: lane-linear 16B reads, conflict-free
    bh8 af[4];
#pragma unroll
    for (int kt = 0; kt < 4; kt++)
      af[kt] = *(const bh8*)(h_frag + kt * 512 + lane * 8);
    f32x4 acc[4] = {};
#pragma unroll
    for (int n = 0; n < 4; n++)
#pragma unroll
      for (int kt = 0; kt < 4; kt++)
        acc[n] = __builtin_amdgcn_mfma_f32_16x16x32_bf16(af[kt], bfr[n][kt], acc[n], 0, 0, 0);
    // C rows 0..1 (valid batches) live in lanes hi==0, reg r=0..1
    if (hi == 0) {
#pragma unroll
      for (int n = 0; n < 4; n++)
#pragma unroll
        for (int r = 0; r < 2; r++)
          g_lds[r][w * 64 + n * 16 + cl] = acc[n][r] + gin[n][r] + bs[n];
    }
    __syncthreads();
    if (tid < 256) {
      const float gi = sigmoidf_(g_lds[ub][uj]);
      const float gf = sigmoidf_(g_lds[ub][uj + 128]);
      const float gg = tanh_(g_lds[ub][uj + 256]);
      const float go = sigmoidf_(g_lds[ub][uj + 384]);
      const float c = gf * c_st + gi * gg;
      c_st = c;
      const float hh = go * tanh_(c);
      // h_frag element index: kt=uj>>5, hi2=(uj>>3)&3, b=ub, e=uj&7
      h_frag[(uj >> 5) * 512 + ((uj >> 3) & 3) * 128 + ub * 8 + (uj & 7)] =
          __float2bfloat16(hh);
      outp[((long)(chunk * 2 + ub) * 128 + t) * 256 + colOff + uj] = __float2bfloat16(hh);
    }
    __syncthreads();
  }
}

// ---------------------------------------------------------------------------
// MHA attention core: per (b, head) block. qkv bf16 (32768,768) -> ao bf16
// ---------------------------------------------------------------------------
#define DOT8T(Q, O, KV)                                                        \
  (Q[(O) + 0] * bfu2f((unsigned short)(KV)[0]) +                               \
   Q[(O) + 1] * bfu2f((unsigned short)(KV)[1]) +                               \
   Q[(O) + 2] * bfu2f((unsigned short)(KV)[2]) +                               \
   Q[(O) + 3] * bfu2f((unsigned short)(KV)[3]) +                               \
   Q[(O) + 4] * bfu2f((unsigned short)(KV)[4]) +                               \
   Q[(O) + 5] * bfu2f((unsigned short)(KV)[5]) +                               \
   Q[(O) + 6] * bfu2f((unsigned short)(KV)[6]) +                               \
   Q[(O) + 7] * bfu2f((unsigned short)(KV)[7]))

__global__ __launch_bounds__(256)
void mha_k(const __hip_bfloat16* __restrict__ qkv, __hip_bfloat16* __restrict__ ao) {
  const int bh = blockIdx.x;
  const int b = bh >> 2, hd = bh & 3;
  const int tid = threadIdx.x;
  __shared__ __align__(16) __hip_bfloat16 ks[128 * 68];
  __shared__ __align__(16) __hip_bfloat16 vs[128 * 68];
  __shared__ __align__(16) char xreg[33792];  // q [128][68] bf16, then P [128][132] bf16
  __shared__ float mx_s[2][128], sm_s[2][128];
  const long base = (long)b * 128 * 768 + hd * 64;
  for (int idx = tid; idx < 3072; idx += 256) {
    const int mm = idx >> 10, cc = idx & 1023;
    const int t = cc >> 3, c8 = cc & 7;
    const bh8 val = *(const bh8*)(qkv + base + (long)t * 768 + mm * 256 + c8 * 8);
    __hip_bfloat16* dst = (mm == 0) ? (__hip_bfloat16*)xreg : (mm == 1 ? ks : vs);
    *(bh8*)(dst + t * 68 + c8 * 8) = val;
  }
  __syncthreads();
  const int i = tid & 127;
  const int jh = tid >> 7;
  float qf[64];
#pragma unroll
  for (int kk = 0; kk < 8; kk++) {
    const bh8 v8 = *(const bh8*)((const __hip_bfloat16*)xreg + i * 68 + kk * 8);
#pragma unroll
    for (int e = 0; e < 8; e++) qf[kk * 8 + e] = bfu2f((unsigned short)v8[e]);
  }
  float s[64];
#pragma unroll
  for (int jo = 0; jo < 64; jo++) {
    const int j = jh * 64 + jo;
    float acc = 0.f;
#pragma unroll
    for (int kk = 0; kk < 8; kk++) {
      const bh8 kv = *(const bh8*)(ks + j * 68 + kk * 8);
      acc += DOT8T(qf, kk * 8, kv);
    }
    s[jo] = acc * 0.125f;
  }
  float mx = -1e30f;
#pragma unroll
  for (int jo = 0; jo < 64; jo++) mx = fmaxf(mx, s[jo]);
  mx_s[jh][i] = mx;
  __syncthreads();
  const float m = fmaxf(mx_s[0][i], mx_s[1][i]);
  float sum = 0.f;
#pragma unroll
  for (int jo = 0; jo < 64; jo++) { s[jo] = __expf(s[jo] - m); sum += s[jo]; }
  sm_s[jh][i] = sum;
  __syncthreads();
  const float inv = 1.f / (sm_s[0][i] + sm_s[1][i]);
  __hip_bfloat16* P = (__hip_bfloat16*)xreg;  // q region is dead now (qf loaded
  // before the mx_s barrier, so every thread is past its q reads)
#pragma unroll
  for (int jo = 0; jo < 64; jo += 2) {
    const unsigned u = (unsigned)f2bfu(s[jo] * inv) | ((unsigned)f2bfu(s[jo + 1] * inv) << 16);
    *(unsigned*)(P + i * 132 + jh * 64 + jo) = u;
  }
  __syncthreads();
  const int dh = jh;
  float acc[32];
#pragma unroll
  for (int e = 0; e < 32; e++) acc[e] = 0.f;
  for (int j = 0; j < 128; j++) {
    const float p = bfu2f(*(const unsigned short*)(P + i * 132 + j));
#pragma unroll
    for (int kk = 0; kk < 4; kk++) {
      const bh8 vv = *(const bh8*)(vs + j * 68 + dh * 32 + kk * 8);
      acc[kk * 8 + 0] += p * bfu2f((unsigned short)vv[0]);
      acc[kk * 8 + 1] += p * bfu2f((unsigned short)vv[1]);
      acc[kk * 8 + 2] += p * bfu2f((unsigned short)vv[2]);
      acc[kk * 8 + 3] += p * bfu2f((unsigned short)vv[3]);
      acc[kk * 8 + 4] += p * bfu2f((unsigned short)vv[4]);
      acc[kk * 8 + 5] += p * bfu2f((unsigned short)vv[5]);
      acc[kk * 8 + 6] += p * bfu2f((unsigned short)vv[6]);
      acc[kk * 8 + 7] += p * bfu2f((unsigned short)vv[7]);
    }
  }
  const long ob = ((long)b * 128 + i) * 256 + hd * 64 + dh * 32;
#pragma unroll
  for (int kk = 0; kk < 16; kk++) {
    const unsigned u = (unsigned)f2bfu(acc[2 * kk]) | ((unsigned)f2bfu(acc[2 * kk + 1]) << 16);
    *(unsigned*)(ao + ob + kk * 2) = u;
  }
}

// ---------------------------------------------------------------------------
// residual + LayerNorm(256):  att = LN(proj + out1)
// ---------------------------------------------------------------------------
__global__ __launch_bounds__(256)
void resid_ln_k(const float* __restrict__ proj, const __hip_bfloat16* __restrict__ o,
                const float* __restrict__ g, const float* __restrict__ bb,
                float* __restrict__ att) {
  const long m = blockIdx.x;
  const int t = threadIdx.x;
  const float v = proj[m * 256 + t] + __bfloat162float(o[m * 256 + t]);
  float sv = v, ssv = v * v;
#pragma unroll
  for (int mm = 1; mm < 64; mm <<= 1) { sv += __shfl_xor(sv, mm); ssv += __shfl_xor(ssv, mm); }
  __shared__ float red[4][2];
  const int lane = t & 63, wv = t >> 6;
  if (lane == 0) { red[wv][0] = sv; red[wv][1] = ssv; }
  __syncthreads();
  const float S = red[0][0] + red[1][0] + red[2][0] + red[3][0];
  const float SS = red[0][1] + red[1][1] + red[2][1] + red[3][1];
  const float mu = S * (1.f / 256.f);
  const float rr = rsqrtf(SS * (1.f / 256.f) - mu * mu + 1e-5f);
  att[m * 256 + t] = (v - mu) * rr * g[t] + bb[t];
}

// ---------------------------------------------------------------------------
// pooling (mean+max over t) -> LN(512) -> fc1+relu -> fc2 -> d_out[b]
// ---------------------------------------------------------------------------
__global__ __launch_bounds__(256)
void pool_k(const float* __restrict__ att, const float* __restrict__ png,
            const float* __restrict__ pnb, const float* __restrict__ f1w,
            const float* __restrict__ f1b, const float* __restrict__ f2w,
            const float* __restrict__ f2b, float* __restrict__ outp) {
  const int b = blockIdx.x, e = threadIdx.x;
  float sum = 0.f, mx = -1e30f;
  for (int t = 0; t < 128; t++) {
    const float v = att[((long)b * 128 + t) * 256 + e];
    sum += v; mx = fmaxf(mx, v);
  }
  const float a0 = sum * (1.f / 128.f), a1 = mx;
  float sv = a0 + a1, ssv = a0 * a0 + a1 * a1;
#pragma unroll
  for (int mm = 1; mm < 64; mm <<= 1) { sv += __shfl_xor(sv, mm); ssv += __shfl_xor(ssv, mm); }
  __shared__ float red[4][2];
  __shared__ float y[512];
  __shared__ float z[128];
  const int lane = e & 63, wv = e >> 6;
  if (lane == 0) { red[wv][0] = sv; red[wv][1] = ssv; }
  __syncthreads();
  const float S = red[0][0] + red[1][0] + red[2][0] + red[3][0];
  const float SS = red[0][1] + red[1][1] + red[2][1] + red[3][1];
  const float mu = S * (1.f / 512.f);
  const float rr = rsqrtf(SS * (1.f / 512.f) - mu * mu + 1e-5f);
  y[e] = (a0 - mu) * rr * png[e] + pnb[e];
  y[256 + e] = (a1 - mu) * rr * png[256 + e] + pnb[256 + e];
  __syncthreads();
  if (e < 128) {
    float a = f1b[e];
    for (int k = 0; k < 512; k++) a += y[k] * f1w[e * 512 + k];
    z[e] = fmaxf(a, 0.f);
  }
  __syncthreads();
  if (e < 64) {
    float p = z[e] * f2w[e] + z[e + 64] * f2w[e + 64];
#pragma unroll
    for (int mm = 1; mm < 64; mm <<= 1) p += __shfl_xor(p, mm);
    if (e == 0) outp[b] = p + f2b[0];
  }
}

// ---------------------------------------------------------------------------
// Host orchestration
// ---------------------------------------------------------------------------
extern "C" void kernel_launch(void* const* d_in, const int* in_sizes, int n_in,
                              void* d_out, int out_size, void* d_ws, size_t ws_size,
                              hipStream_t stream) {
  (void)in_sizes; (void)n_in; (void)out_size; (void)ws_size;
  const float* x      = (const float*)d_in[0];
  const float* c1w    = (const float*)d_in[1];
  const float* c1b    = (const float*)d_in[2];
  const float* bn1g   = (const float*)d_in[3];
  const float* bn1b   = (const float*)d_in[4];
  const float* c2w    = (const float*)d_in[5];
  const float* c2b    = (const float*)d_in[6];
  const float* bn2g   = (const float*)d_in[7];
  const float* bn2b   = (const float*)d_in[8];
  const float* g1W    = (const float*)d_in[9];
  const float* g1asrc = (const float*)d_in[10];
  const float* g1adst = (const float*)d_in[11];
  const float* g1adj  = (const float*)d_in[12];
  const float* n1g    = (const float*)d_in[13];
  const float* n1b    = (const float*)d_in[14];
  const float* g2W    = (const float*)d_in[15];
  const float* g2asrc = (const float*)d_in[16];
  const float* g2adst = (const float*)d_in[17];
  const float* g2adj  = (const float*)d_in[18];
  const float* n2g    = (const float*)d_in[19];
  const float* n2b    = (const float*)d_in[20];
  const float* l0fWih = (const float*)d_in[21];
  const float* l0fWhh = (const float*)d_in[22];
  const float* l0fbih = (const float*)d_in[23];
  const float* l0fbhh = (const float*)d_in[24];
  const float* l0rWih = (const float*)d_in[25];
  const float* l0rWhh = (const float*)d_in[26];
  const float* l0rbih = (const float*)d_in[27];
  const float* l0rbhh = (const float*)d_in[28];
  const float* l1fWih = (const float*)d_in[29];
  const float* l1fWhh = (const float*)d_in[30];
  const float* l1fbih = (const float*)d_in[31];
  const float* l1fbhh = (const float*)d_in[32];
  const float* l1rWih = (const float*)d_in[33];
  const float* l1rWhh = (const float*)d_in[34];
  const float* l1rbih = (const float*)d_in[35];
  const float* l1rbhh = (const float*)d_in[36];
  const float* wqkv   = (const float*)d_in[37];
  const float* bqkv   = (const float*)d_in[38];
  const float* wo     = (const float*)d_in[39];
  const float* bo     = (const float*)d_in[40];
  const float* ang    = (const float*)d_in[41];
  const float* anb    = (const float*)d_in[42];
  const float* png    = (const float*)d_in[43];
  const float* pnb    = (const float*)d_in[44];
  const float* f1w    = (const float*)d_in[45];
  const float* f1b    = (const float*)d_in[46];
  const float* f2w    = (const float*)d_in[47];
  const float* f2b    = (const float*)d_in[48];

  char* ws = (char*)d_ws;
  // Buffer overlay plan (total 223,395,840 B; lifetimes verified per stage):
  //  [0       , 67.1MB ) G0   (conv2 out) ........ then GAF (lstm gates f32)
  //  [67.1MB  , 134.2MB) C1   (conv1 out) ........ then low half of G1O,
  //                                               then OUT1 + QKV
  //  [67.1MB  , 201.3MB) G1O  (GAT out, (32768,2048) bf16, in-place gat2)
  //  [134.2MB , 218.1MB)      then AOb, PROJ, ATT
  //  [201.3MB , 218.1MB) OUT0 (lstm0 out)
  //  [218.1MB , 223.4MB) bf16 weights (persistent)
  auto G0   = (__hip_bfloat16*)(ws + 0L);
  auto C1   = (__hip_bfloat16*)(ws + 67108864L);
  auto G1O  = (__hip_bfloat16*)(ws + 67108864L);
  auto GAF  = (float*)(ws + 0L);
  auto OUT0 = (__hip_bfloat16*)(ws + 201326592L);
  auto OUT1 = (__hip_bfloat16*)(ws + 67108864L);
  auto QKV  = (__hip_bfloat16*)(ws + 83886080L);
  auto AOb  = (__hip_bfloat16*)(ws + 134217728L);
  auto PROJ = (float*)(ws + 150994944L);
  auto ATT  = (float*)(ws + 184549376L);
  char* WB  = ws + 218103808L;
  auto WG1T  = (__hip_bfloat16*)(WB + 0);        // (128,64)  = g1_W^T
  auto WG2T  = (__hip_bfloat16*)(WB + 16384);    // (128,128) = g2_W^T
  auto WI0F  = (__hip_bfloat16*)(WB + 49152);    // (512,2048)
  auto WI0R  = (__hip_bfloat16*)(WB + 2146304);
  auto WI1F  = (__hip_bfloat16*)(WB + 4243456);  // (512,256)
  auto WI1R  = (__hip_bfloat16*)(WB + 4505600);
  auto WQKVb = (__hip_bfloat16*)(WB + 4767744);  // (768,256)
  auto WOb   = (__hip_bfloat16*)(WB + 5160960);  // (256,256)

  // --- weight prep (bf16; Wih/wqkv/wo are already (N,K) = B^T layout) ---
  tr_bf16_k<<<32, 256, 0, stream>>>(g1W, WG1T, 64, 128);
  tr_bf16_k<<<64, 256, 0, stream>>>(g2W, WG2T, 128, 128);
  cvt_bf16_k<<<4096, 256, 0, stream>>>(l0fWih, WI0F, 1048576);
  cvt_bf16_k<<<4096, 256, 0, stream>>>(l0rWih, WI0R, 1048576);
  cvt_bf16_k<<<512, 256, 0, stream>>>(l1fWih, WI1F, 131072);
  cvt_bf16_k<<<512, 256, 0, stream>>>(l1rWih, WI1R, 131072);
  cvt_bf16_k<<<768, 256, 0, stream>>>(wqkv, WQKVb, 196608);
  cvt_bf16_k<<<256, 256, 0, stream>>>(wo, WOb, 65536);

  // --- pipeline ---
  conv1_k<<<4096, 256, 0, stream>>>(x, c1w, c1b, bn1g, bn1b, C1);
  conv2_k<<<4096, 256, 0, stream>>>(C1, c2w, c2b, bn2g, bn2b, G0);
  gat_fused_k<64><<<32768, 128, 0, stream>>>(G0, WG1T, g1asrc, g1adst, g1adj, n1g, n1b, G1O);
  gat_fused_k<128><<<32768, 128, 0, stream>>>(G1O, WG2T, g2asrc, g2adst, g2adj, n2g, n2b, G1O);
  // LSTM layer 0 (dirs serialized on one gate buffer)
  gemm_bt<false><<<dim3(4, 256), 256, 0, stream>>>(G1O, WI0F, GAF, nullptr, 32768, 512, 2048);
  lstm_mfma_k<<<128, 512, 0, stream>>>(GAF, l0fWhh, l0fbih, l0fbhh, OUT0, 0, 0);
  gemm_bt<false><<<dim3(4, 256), 256, 0, stream>>>(G1O, WI0R, GAF, nullptr, 32768, 512, 2048);
  lstm_mfma_k<<<128, 512, 0, stream>>>(GAF, l0rWhh, l0rbih, l0rbhh, OUT0, 1, 128);
  // LSTM layer 1
  gemm_bt<false><<<dim3(4, 256), 256, 0, stream>>>(OUT0, WI1F, GAF, nullptr, 32768, 512, 256);
  lstm_mfma_k<<<128, 512, 0, stream>>>(GAF, l1fWhh, l1fbih, l1fbhh, OUT1, 0, 0);
  gemm_bt<false><<<dim3(4, 256), 256, 0, stream>>>(OUT0, WI1R, GAF, nullptr, 32768, 512, 256);
  lstm_mfma_k<<<128, 512, 0, stream>>>(GAF, l1rWhh, l1rbih, l1rbhh, OUT1, 1, 128);
  // MHA block
  gemm_bt<true><<<dim3(6, 256), 256, 0, stream>>>(OUT1, WQKVb, QKV, bqkv, 32768, 768, 256);
  mha_k<<<1024, 256, 0, stream>>>(QKV, AOb);
  gemm_bt<false><<<dim3(2, 256), 256, 0, stream>>>(AOb, WOb, PROJ, bo, 32768, 256, 256);
  resid_ln_k<<<32768, 256, 0, stream>>>(PROJ, OUT1, ang, anb, ATT);
  pool_k<<<256, 256, 0, stream>>>(ATT, png, pnb, f1w, f1b, f2w, f2b, (float*)d_out);
}

// Round 6
// 1706.182 us; speedup vs baseline: 2.2492x; 1.2360x over previous
//
#include <hip/hip_runtime.h>
#include <hip/hip_bf16.h>
#include <stdint.h>

// ---------------------------------------------------------------------------
// M6_GraphBiLSTM: conv1 -> conv2 -> GAT x2 -> BiLSTM x2 -> MHA -> pool -> FC
// Round 6: GAT kernel v2.
//   R5 profile: gat_fused_k x2 @397us = 38% (VALU 32%, MfmaUtil 2%, 7.3M LDS
//   bank conflicts; ~5K-cycle serial shfl chains per block).
//   v2: es/ed folded into the projection MFMA via augmented weights
//   (gat_waug_k builds [W^T | W@asrc | W@adst] rows), LN via LDS-transpose
//   partial sums (3 shfl levels), a_s padded to stride 65 (conflict-free).
// Shapes: B=256, C=16, T=256, TC=128, H=128, HEADS=4, D=32, E=256
// ---------------------------------------------------------------------------

typedef __attribute__((ext_vector_type(8))) short bh8;    // 8 x bf16 (4 VGPR)
typedef __attribute__((ext_vector_type(4))) float f32x4;  // MFMA accumulator

__device__ __forceinline__ float bfu2f(unsigned short u) {
  union { unsigned u; float f; } x; x.u = ((unsigned)u) << 16; return x.f;
}
__device__ __forceinline__ unsigned short f2bfu(float f) {
  __hip_bfloat16 h = __float2bfloat16(f);
  return *reinterpret_cast<unsigned short*>(&h);
}
__device__ __forceinline__ float geluf(float v) {
  return 0.5f * v * (1.f + erff(v * 0.70710678118f));
}
__device__ __forceinline__ float sigmoidf_(float x) { return 1.f / (1.f + __expf(-x)); }
__device__ __forceinline__ float tanh_(float x) {
  x = fminf(fmaxf(x, -30.f), 30.f);
  float e = __expf(2.f * x);
  return (e - 1.f) / (e + 1.f);
}

// async global->LDS, 16B per lane; LDS dest = wave-uniform base + lane*16
__device__ __forceinline__ void g2l16(const void* g, void* l) {
  __builtin_amdgcn_global_load_lds(
      (const __attribute__((address_space(1))) unsigned int*)g,
      (__attribute__((address_space(3))) unsigned int*)l, 16, 0, 0);
}

// ---------------------------------------------------------------------------
// Weight prep
// ---------------------------------------------------------------------------
__global__ __launch_bounds__(256) void cvt_bf16_k(const float* __restrict__ s,
                                                  __hip_bfloat16* __restrict__ d, int n) {
  int i = blockIdx.x * 256 + threadIdx.x;
  if (i < n) d[i] = __float2bfloat16(s[i]);
}

// Augmented GAT weight: waug (144 rows x K) bf16.
//   rows 0..127  : W^T              (waug[f][k] = W[k][f])
//   rows 128..131: (W @ asrc_h)^T   (es weights per head h)
//   rows 132..135: (W @ adst_h)^T   (ed weights per head h)
//   rows 136..143: zero pad
__global__ __launch_bounds__(256)
void gat_waug_k(const float* __restrict__ W, const float* __restrict__ asrc,
                const float* __restrict__ adst, __hip_bfloat16* __restrict__ waug,
                int K) {
  int idx = blockIdx.x * 256 + threadIdx.x;
  if (idx >= 144 * K) return;
  const int row = idx / K, k = idx % K;
  float v = 0.f;
  if (row < 128) {
    v = W[k * 128 + row];
  } else if (row < 136) {
    const int h = (row - 128) & 3;
    const float* av = (row < 132) ? asrc : adst;
    for (int d = 0; d < 32; d++) v += W[k * 128 + h * 32 + d] * av[h * 32 + d];
  }
  waug[row * K + k] = __float2bfloat16(v);
}

// ---------------------------------------------------------------------------
// conv1 (k=7, pad 3) + BN + GELU.  x:(4096,256) f32 -> c1:(4096,32,256) bf16
// ---------------------------------------------------------------------------
__global__ __launch_bounds__(256)
void conv1_k(const float* __restrict__ x, const float* __restrict__ w,
             const float* __restrict__ b, const float* __restrict__ g,
             const float* __restrict__ bb, __hip_bfloat16* __restrict__ c1) {
  __shared__ float xs[264];
  const int nn = blockIdx.x, t = threadIdx.x;
  xs[3 + t] = x[nn * 256 + t];
  if (t < 3) { xs[t] = 0.f; xs[259 + t] = 0.f; }
  __syncthreads();
  for (int oc = 0; oc < 32; oc++) {
    float acc = 0.f;
#pragma unroll
    for (int k = 0; k < 7; k++) acc += xs[t + k] * w[oc * 7 + k];
    float v = (acc + b[oc]) * g[oc] + bb[oc];
    c1[(nn * 32 + oc) * 256 + t] = __float2bfloat16(geluf(v));
  }
}

// ---------------------------------------------------------------------------
// conv2 (k=5, s=2, pad 2) + BN + GELU.  c1 bf16 -> g0 bf16 in GAT layout:
// g0[((b*128+to)*16 + c)*64 + oc],  nn = b*16+c
// ---------------------------------------------------------------------------
__global__ __launch_bounds__(256)
void conv2_k(const __hip_bfloat16* __restrict__ c1, const float* __restrict__ w2,
             const float* __restrict__ b2, const float* __restrict__ g2,
             const float* __restrict__ bb2, __hip_bfloat16* __restrict__ g0) {
  __shared__ float ins[32 * 264];   // [ic][264], data at +2, zeros at 0,1,258,259
  __shared__ float wsh[64 * 161];   // [oc][161] padded (161 % 32 == 1)
  const int nn = blockIdx.x, tid = threadIdx.x;
  for (int idx = tid; idx < 64 * 160; idx += 256)
    wsh[(idx / 160) * 161 + idx % 160] = w2[idx];
  for (int idx = tid; idx < 32 * 4; idx += 256) {
    int ic = idx >> 2, p = idx & 3;
    ins[ic * 264 + (p < 2 ? p : 256 + p)] = 0.f;
  }
  for (int idx = tid; idx < 32 * 256; idx += 256) {
    int ic = idx >> 8, xq = idx & 255;
    ins[ic * 264 + 2 + xq] = __bfloat162float(c1[(nn * 32 + ic) * 256 + xq]);
  }
  __syncthreads();
  const int oc = tid & 63, tq = tid >> 6;
  float acc[32];
#pragma unroll
  for (int jj = 0; jj < 32; jj++) acc[jj] = 0.f;
  for (int ic = 0; ic < 32; ic++) {
    float wk0 = wsh[oc * 161 + ic * 5 + 0], wk1 = wsh[oc * 161 + ic * 5 + 1];
    float wk2 = wsh[oc * 161 + ic * 5 + 2], wk3 = wsh[oc * 161 + ic * 5 + 3];
    float wk4 = wsh[oc * 161 + ic * 5 + 4];
    const float* row = &ins[ic * 264];
#pragma unroll
    for (int jj = 0; jj < 32; jj++) {
      const int xb = tq * 64 + 2 * jj;  // = 2*to
      acc[jj] += row[xb] * wk0 + row[xb + 1] * wk1 + row[xb + 2] * wk2 +
                 row[xb + 3] * wk3 + row[xb + 4] * wk4;
    }
  }
  const int b = nn >> 4, c = nn & 15;
  const float gg = g2[oc], bbv = bb2[oc], bs = b2[oc];
#pragma unroll
  for (int jj = 0; jj < 32; jj++) {
    const int to = tq * 32 + jj;
    float v = (acc[jj] + bs) * gg + bbv;
    g0[((long)(b * 128 + to) * 16 + c) * 64 + oc] = __float2bfloat16(geluf(v));
  }
}

// ---------------------------------------------------------------------------
// bf16 MFMA GEMM:  C(M,N) = A(M,K) @ B(N,K)^T  (+bias[N]), m97 structure.
// 128x128 tile, BK=32, 4 waves (2x2), 16x16x32 MFMA, global_load_lds staging.
// ---------------------------------------------------------------------------
template <bool OUT_BF16>
__global__ __launch_bounds__(256)
void gemm_bt(const __hip_bfloat16* __restrict__ A, const __hip_bfloat16* __restrict__ Bm,
             void* __restrict__ Cout, const float* __restrict__ bias,
             int M, int N, int K) {
  __shared__ __align__(16) __hip_bfloat16 sA[128 * 32];
  __shared__ __align__(16) __hip_bfloat16 sB[128 * 32];
  const int tid = threadIdx.x;
  const int lane = tid & 63, wv = tid >> 6;
  const int wr = wv >> 1, wc = wv & 1;
  const long m0 = (long)blockIdx.y * 128;
  const long n0 = (long)blockIdx.x * 128;
  // staging: 512 16B-chunks per matrix; this thread owns 2 (q=0,1)
  const int sa0 = wv * 128 + lane, sa1 = wv * 128 + 64 + lane;
  const int ra0 = sa0 >> 2, ca0 = sa0 & 3;
  const int ra1 = sa1 >> 2, ca1 = sa1 & 3;
  const __hip_bfloat16* a0 = A + (m0 + ra0) * K + ca0 * 8;
  const __hip_bfloat16* a1 = A + (m0 + ra1) * K + ca1 * 8;
  const __hip_bfloat16* b0 = Bm + (n0 + ra0) * K + ca0 * 8;
  const __hip_bfloat16* b1 = Bm + (n0 + ra1) * K + ca1 * 8;
  char* lA0 = (char*)sA + wv * 2048;
  char* lA1 = (char*)sA + wv * 2048 + 1024;
  char* lB0 = (char*)sB + wv * 2048;
  char* lB1 = (char*)sB + wv * 2048 + 1024;
  f32x4 acc[4][4] = {};
  const int rfA = wr * 64 + (lane & 15);
  const int rfB = wc * 64 + (lane & 15);
  const int kf = (lane >> 4) * 8;
  for (int kt = 0; kt < K; kt += 32) {
    __syncthreads();
    g2l16(a0 + kt, lA0);
    g2l16(a1 + kt, lA1);
    g2l16(b0 + kt, lB0);
    g2l16(b1 + kt, lB1);
    __syncthreads();
    bh8 af[4], bf[4];
#pragma unroll
    for (int m = 0; m < 4; m++) af[m] = *(const bh8*)(sA + (rfA + m * 16) * 32 + kf);
#pragma unroll
    for (int n = 0; n < 4; n++) bf[n] = *(const bh8*)(sB + (rfB + n * 16) * 32 + kf);
#pragma unroll
    for (int m = 0; m < 4; m++)
#pragma unroll
      for (int n = 0; n < 4; n++)
        acc[m][n] = __builtin_amdgcn_mfma_f32_16x16x32_bf16(af[m], bf[n], acc[m][n], 0, 0, 0);
  }
#pragma unroll
  for (int n = 0; n < 4; n++) {
    const long col = n0 + wc * 64 + n * 16 + (lane & 15);
    const float bv = bias ? bias[col] : 0.f;
#pragma unroll
    for (int m = 0; m < 4; m++) {
      const long row0 = m0 + wr * 64 + m * 16 + ((lane >> 4) * 4);
#pragma unroll
      for (int r = 0; r < 4; r++) {
        float v = acc[m][n][r] + bv;
        if (OUT_BF16)
          ((__hip_bfloat16*)Cout)[(row0 + r) * N + col] = __float2bfloat16(v);
        else
          ((float*)Cout)[(row0 + r) * N + col] = v;
      }
    }
  }
}

// ---------------------------------------------------------------------------
// Fused GAT layer v2 (per n of 32768): [h | es | ed] = h_in(16,K) @ WAUG via
// MFMA (es/ed folded into the GEMM), then softmax-attn, ReLU, LayerNorm(128).
// waug is (144,K) bf16. In-place safe (reads before first barrier, writes last).
// ---------------------------------------------------------------------------
template <int K>
__global__ __launch_bounds__(128)
void gat_fused_k(const __hip_bfloat16* __restrict__ hin,
                 const __hip_bfloat16* __restrict__ waug,
                 const float* __restrict__ adj, const float* __restrict__ lng,
                 const float* __restrict__ lnb, __hip_bfloat16* __restrict__ outp) {
  const long n = blockIdx.x;
  const int f = threadIdx.x;          // 0..127, f = head*32 + d
  const int lane = f & 63, wv = f >> 6;
  const int head = f >> 5;
  __shared__ float hs[16][132];       // projected h (then reused for o)
  __shared__ float adj_s[16][16];
  __shared__ float es_s[16][4], ed_s[16][4];
  __shared__ float a_s[16][65];       // stride 65: bank = (i+4j+hd)%32, CF
  __shared__ float mean_s[16], rs_s[16];
  // --- projection: wave wv -> feature cols wv*64..wv*64+63; wave0 also the
  //     es/ed tile (waug rows 128..143) ---
  const __hip_bfloat16* An = hin + n * 16 * K;
  const int ar = lane & 15, hi = lane >> 4, ak = hi * 8;
  f32x4 pacc[4] = {};
  f32x4 pe = {};
  for (int kt = 0; kt < K; kt += 32) {
    const bh8 af = *(const bh8*)(An + ar * K + kt + ak);
#pragma unroll
    for (int s = 0; s < 4; s++) {
      const bh8 bf = *(const bh8*)(waug + (wv * 64 + s * 16 + ar) * K + kt + ak);
      pacc[s] = __builtin_amdgcn_mfma_f32_16x16x32_bf16(af, bf, pacc[s], 0, 0, 0);
    }
    if (wv == 0) {
      const bh8 be = *(const bh8*)(waug + (128 + ar) * K + kt + ak);
      pe = __builtin_amdgcn_mfma_f32_16x16x32_bf16(af, be, pe, 0, 0, 0);
    }
  }
  for (int idx = f; idx < 256; idx += 128) adj_s[idx >> 4][idx & 15] = adj[idx];
#pragma unroll
  for (int s = 0; s < 4; s++)
#pragma unroll
    for (int r = 0; r < 4; r++)
      hs[hi * 4 + r][wv * 64 + s * 16 + ar] = pacc[s][r];
  if (wv == 0 && ar < 8) {
#pragma unroll
    for (int r = 0; r < 4; r++) {
      const int c = hi * 4 + r;
      if (ar < 4) es_s[c][ar] = pe[r];
      else        ed_s[c][ar - 4] = pe[r];
    }
  }
  __syncthreads();
  // --- softmax over j (64 threads: i = f>>2, hd = f&3) ---
  if (f < 64) {
    const int i = f >> 2, hd = f & 3;
    float ev[16], mx = -1e30f;
#pragma unroll
    for (int j = 0; j < 16; j++) {
      float e = es_s[i][hd] + ed_s[j][hd];
      e = (e > 0.f ? e : 0.2f * e) + adj_s[i][j];
      ev[j] = e; mx = fmaxf(mx, e);
    }
    float sm = 0.f;
#pragma unroll
    for (int j = 0; j < 16; j++) { ev[j] = __expf(ev[j] - mx); sm += ev[j]; }
    const float inv = 1.f / sm;
#pragma unroll
    for (int j = 0; j < 16; j++) a_s[i][j * 4 + hd] = ev[j] * inv;
  }
  __syncthreads();
  // --- PV + ReLU (thread f owns feature f for all 16 channels) ---
  float hv[16];
#pragma unroll
  for (int c = 0; c < 16; c++) hv[c] = hs[c][f];
  __syncthreads();   // all hs reads done before o overwrites hs
  float o[16];
#pragma unroll
  for (int i = 0; i < 16; i++) {
    float acc = 0.f;
#pragma unroll
    for (int j = 0; j < 16; j++) acc += a_s[i][j * 4 + head] * hv[j];
    acc = fmaxf(acc, 0.f);
    o[i] = acc;
    hs[i][f] = acc;
  }
  __syncthreads();
  // --- LN stats via LDS transpose: thread (i = t>>3, g = t&7) sums 16 f ---
  {
    const int i = f >> 3, g = f & 7;
    float s = 0.f, ss = 0.f;
#pragma unroll
    for (int q = 0; q < 16; q++) {
      const float v = hs[i][g * 16 + q];
      s += v; ss += v * v;
    }
#pragma unroll
    for (int m = 1; m < 8; m <<= 1) { s += __shfl_xor(s, m); ss += __shfl_xor(ss, m); }
    if (g == 0) {
      const float mean = s * (1.f / 128.f);
      const float var = ss * (1.f / 128.f) - mean * mean;
      mean_s[i] = mean;
      rs_s[i] = rsqrtf(var + 1e-5f);
    }
  }
  __syncthreads();
  const float gw = lng[f], gb = lnb[f];
#pragma unroll
  for (int i = 0; i < 16; i++)
    outp[(n * 16 + i) * 128 + f] = __float2bfloat16((o[i] - mean_s[i]) * rs_s[i] * gw + gb);
}

// ---------------------------------------------------------------------------
// BiLSTM recurrence via MFMA, ONE direction. Gates (x@Wih^T) precomputed f32.
// Grid: 128 blocks (chunk = 2 sequences), 512 threads = 8 waves.
// Wave w owns gate columns [w*64, w*64+64): Whh^T held in registers as 16
// MFMA B-frags (64 VGPR). h kept bf16 in LDS in A-frag layout [kt][hi][b][e]
// (lane-linear 1024B reads per k-tile, conflict-free). c state f32 in regs.
// ---------------------------------------------------------------------------
__global__ __launch_bounds__(512)
void lstm_mfma_k(const float* __restrict__ gates, const float* __restrict__ whh,
                 const float* __restrict__ bih, const float* __restrict__ bhh,
                 __hip_bfloat16* __restrict__ outp, const int dir, const int colOff) {
  const int chunk = blockIdx.x;            // sequences 2*chunk, 2*chunk+1
  const int tid = threadIdx.x;
  const int lane = tid & 63, w = tid >> 6;
  const int cl = lane & 15, hi = lane >> 4;
  __shared__ __align__(16) __hip_bfloat16 h_frag[2048];  // [kt][hi][b][e]=[4][4][16][8]
  __shared__ float g_lds[2][520];                        // [batch][gate j]
  // zero h state (rows b>=2 stay zero forever -> harmless MFMA garbage rows)
  for (int idx = tid; idx < 1024; idx += 512) ((unsigned*)h_frag)[idx] = 0u;
  // B-frags: lane holds Whh^T[j = w*64+n*16+cl][k = kt*32+hi*8 .. +8] as bf16x8
  bh8 bfr[4][4];
#pragma unroll
  for (int n = 0; n < 4; n++)
#pragma unroll
    for (int kt = 0; kt < 4; kt++) {
      const float* wp = whh + (w * 64 + n * 16 + cl) * 128 + kt * 32 + hi * 8;
      const float4 lo = *(const float4*)wp;
      const float4 hv = *(const float4*)(wp + 4);
      bh8 r;
      r[0] = (short)f2bfu(lo.x); r[1] = (short)f2bfu(lo.y);
      r[2] = (short)f2bfu(lo.z); r[3] = (short)f2bfu(lo.w);
      r[4] = (short)f2bfu(hv.x); r[5] = (short)f2bfu(hv.y);
      r[6] = (short)f2bfu(hv.z); r[7] = (short)f2bfu(hv.w);
      bfr[n][kt] = r;
    }
  float bs[4];
#pragma unroll
  for (int n = 0; n < 4; n++)
    bs[n] = bih[w * 64 + n * 16 + cl] + bhh[w * 64 + n * 16 + cl];
  const int ub = tid >> 7, uj = tid & 127;  // cell mapping (batch, h-unit), tid<256
  float c_st = 0.f;
  __syncthreads();
  for (int s = 0; s < 128; s++) {
    const int t = dir ? (127 - s) : s;
    // x-gate inputs for this step (only hi==0 lanes consume; issue early)
    float gin[4][2];
    if (hi == 0) {
#pragma unroll
      for (int n = 0; n < 4; n++)
#pragma unroll
        for (int r = 0; r < 2; r++)
          gin[n][r] = gates[((long)(chunk * 2 + r) * 128 + t) * 512 + w * 64 + n * 16 + cl];
    }
    // A-frags: lane-linear 16B reads, conflict-free
    bh8 af[4];
#pragma unroll
    for (int kt = 0; kt < 4; kt++)
      af[kt] = *(const bh8*)(h_frag + kt * 512 + lane * 8);
    f32x4 acc[4] = {};
#pragma unroll
    for (int n = 0; n < 4; n++)
#pragma unroll
      for (int kt = 0; kt < 4; kt++)
        acc[n] = __builtin_amdgcn_mfma_f32_16x16x32_bf16(af[kt], bfr[n][kt], acc[n], 0, 0, 0);
    // C rows 0..1 (valid batches) live in lanes hi==0, reg r=0..1
    if (hi == 0) {
#pragma unroll
      for (int n = 0; n < 4; n++)
#pragma unroll
        for (int r = 0; r < 2; r++)
          g_lds[r][w * 64 + n * 16 + cl] = acc[n][r] + gin[n][r] + bs[n];
    }
    __syncthreads();
    if (tid < 256) {
      const float gi = sigmoidf_(g_lds[ub][uj]);
      const float gf = sigmoidf_(g_lds[ub][uj + 128]);
      const float gg = tanh_(g_lds[ub][uj + 256]);
      const float go = sigmoidf_(g_lds[ub][uj + 384]);
      const float c = gf * c_st + gi * gg;
      c_st = c;
      const float hh = go * tanh_(c);
      // h_frag element index: kt=uj>>5, hi2=(uj>>3)&3, b=ub, e=uj&7
      h_frag[(uj >> 5) * 512 + ((uj >> 3) & 3) * 128 + ub * 8 + (uj & 7)] =
          __float2bfloat16(hh);
      outp[((long)(chunk * 2 + ub) * 128 + t) * 256 + colOff + uj] = __float2bfloat16(hh);
    }
    __syncthreads();
  }
}

// ---------------------------------------------------------------------------
// MHA attention core: per (b, head) block. qkv bf16 (32768,768) -> ao bf16
// ---------------------------------------------------------------------------
#define DOT8T(Q, O, KV)                                                        \
  (Q[(O) + 0] * bfu2f((unsigned short)(KV)[0]) +                               \
   Q[(O) + 1] * bfu2f((unsigned short)(KV)[1]) +                               \
   Q[(O) + 2] * bfu2f((unsigned short)(KV)[2]) +                               \
   Q[(O) + 3] * bfu2f((unsigned short)(KV)[3]) +                               \
   Q[(O) + 4] * bfu2f((unsigned short)(KV)[4]) +                               \
   Q[(O) + 5] * bfu2f((unsigned short)(KV)[5]) +                               \
   Q[(O) + 6] * bfu2f((unsigned short)(KV)[6]) +                               \
   Q[(O) + 7] * bfu2f((unsigned short)(KV)[7]))

__global__ __launch_bounds__(256)
void mha_k(const __hip_bfloat16* __restrict__ qkv, __hip_bfloat16* __restrict__ ao) {
  const int bh = blockIdx.x;
  const int b = bh >> 2, hd = bh & 3;
  const int tid = threadIdx.x;
  __shared__ __align__(16) __hip_bfloat16 ks[128 * 68];
  __shared__ __align__(16) __hip_bfloat16 vs[128 * 68];
  __shared__ __align__(16) char xreg[33792];  // q [128][68] bf16, then P [128][132] bf16
  __shared__ float mx_s[2][128], sm_s[2][128];
  const long base = (long)b * 128 * 768 + hd * 64;
  for (int idx = tid; idx < 3072; idx += 256) {
    const int mm = idx >> 10, cc = idx & 1023;
    const int t = cc >> 3, c8 = cc & 7;
    const bh8 val = *(const bh8*)(qkv + base + (long)t * 768 + mm * 256 + c8 * 8);
    __hip_bfloat16* dst = (mm == 0) ? (__hip_bfloat16*)xreg : (mm == 1 ? ks : vs);
    *(bh8*)(dst + t * 68 + c8 * 8) = val;
  }
  __syncthreads();
  const int i = tid & 127;
  const int jh = tid >> 7;
  float qf[64];
#pragma unroll
  for (int kk = 0; kk < 8; kk++) {
    const bh8 v8 = *(const bh8*)((const __hip_bfloat16*)xreg + i * 68 + kk * 8);
#pragma unroll
    for (int e = 0; e < 8; e++) qf[kk * 8 + e] = bfu2f((unsigned short)v8[e]);
  }
  float s[64];
#pragma unroll
  for (int jo = 0; jo < 64; jo++) {
    const int j = jh * 64 + jo;
    float acc = 0.f;
#pragma unroll
    for (int kk = 0; kk < 8; kk++) {
      const bh8 kv = *(const bh8*)(ks + j * 68 + kk * 8);
      acc += DOT8T(qf, kk * 8, kv);
    }
    s[jo] = acc * 0.125f;
  }
  float mx = -1e30f;
#pragma unroll
  for (int jo = 0; jo < 64; jo++) mx = fmaxf(mx, s[jo]);
  mx_s[jh][i] = mx;
  __syncthreads();
  const float m = fmaxf(mx_s[0][i], mx_s[1][i]);
  float sum = 0.f;
#pragma unroll
  for (int jo = 0; jo < 64; jo++) { s[jo] = __expf(s[jo] - m); sum += s[jo]; }
  sm_s[jh][i] = sum;
  __syncthreads();
  const float inv = 1.f / (sm_s[0][i] + sm_s[1][i]);
  __hip_bfloat16* P = (__hip_bfloat16*)xreg;  // q region is dead now (qf loaded
  // before the mx_s barrier, so every thread is past its q reads)
#pragma unroll
  for (int jo = 0; jo < 64; jo += 2) {
    const unsigned u = (unsigned)f2bfu(s[jo] * inv) | ((unsigned)f2bfu(s[jo + 1] * inv) << 16);
    *(unsigned*)(P + i * 132 + jh * 64 + jo) = u;
  }
  __syncthreads();
  const int dh = jh;
  float acc[32];
#pragma unroll
  for (int e = 0; e < 32; e++) acc[e] = 0.f;
  for (int j = 0; j < 128; j++) {
    const float p = bfu2f(*(const unsigned short*)(P + i * 132 + j));
#pragma unroll
    for (int kk = 0; kk < 4; kk++) {
      const bh8 vv = *(const bh8*)(vs + j * 68 + dh * 32 + kk * 8);
      acc[kk * 8 + 0] += p * bfu2f((unsigned short)vv[0]);
      acc[kk * 8 + 1] += p * bfu2f((unsigned short)vv[1]);
      acc[kk * 8 + 2] += p * bfu2f((unsigned short)vv[2]);
      acc[kk * 8 + 3] += p * bfu2f((unsigned short)vv[3]);
      acc[kk * 8 + 4] += p * bfu2f((unsigned short)vv[4]);
      acc[kk * 8 + 5] += p * bfu2f((unsigned short)vv[5]);
      acc[kk * 8 + 6] += p * bfu2f((unsigned short)vv[6]);
      acc[kk * 8 + 7] += p * bfu2f((unsigned short)vv[7]);
    }
  }
  const long ob = ((long)b * 128 + i) * 256 + hd * 64 + dh * 32;
#pragma unroll
  for (int kk = 0; kk < 16; kk++) {
    const unsigned u = (unsigned)f2bfu(acc[2 * kk]) | ((unsigned)f2bfu(acc[2 * kk + 1]) << 16);
    *(unsigned*)(ao + ob + kk * 2) = u;
  }
}

// ---------------------------------------------------------------------------
// residual + LayerNorm(256):  att = LN(proj + out1)
// ---------------------------------------------------------------------------
__global__ __launch_bounds__(256)
void resid_ln_k(const float* __restrict__ proj, const __hip_bfloat16* __restrict__ o,
                const float* __restrict__ g, const float* __restrict__ bb,
                float* __restrict__ att) {
  const long m = blockIdx.x;
  const int t = threadIdx.x;
  const float v = proj[m * 256 + t] + __bfloat162float(o[m * 256 + t]);
  float sv = v, ssv = v * v;
#pragma unroll
  for (int mm = 1; mm < 64; mm <<= 1) { sv += __shfl_xor(sv, mm); ssv += __shfl_xor(ssv, mm); }
  __shared__ float red[4][2];
  const int lane = t & 63, wv = t >> 6;
  if (lane == 0) { red[wv][0] = sv; red[wv][1] = ssv; }
  __syncthreads();
  const float S = red[0][0] + red[1][0] + red[2][0] + red[3][0];
  const float SS = red[0][1] + red[1][1] + red[2][1] + red[3][1];
  const float mu = S * (1.f / 256.f);
  const float rr = rsqrtf(SS * (1.f / 256.f) - mu * mu + 1e-5f);
  att[m * 256 + t] = (v - mu) * rr * g[t] + bb[t];
}

// ---------------------------------------------------------------------------
// pooling (mean+max over t) -> LN(512) -> fc1+relu -> fc2 -> d_out[b]
// ---------------------------------------------------------------------------
__global__ __launch_bounds__(256)
void pool_k(const float* __restrict__ att, const float* __restrict__ png,
            const float* __restrict__ pnb, const float* __restrict__ f1w,
            const float* __restrict__ f1b, const float* __restrict__ f2w,
            const float* __restrict__ f2b, float* __restrict__ outp) {
  const int b = blockIdx.x, e = threadIdx.x;
  float sum = 0.f, mx = -1e30f;
  for (int t = 0; t < 128; t++) {
    const float v = att[((long)b * 128 + t) * 256 + e];
    sum += v; mx = fmaxf(mx, v);
  }
  const float a0 = sum * (1.f / 128.f), a1 = mx;
  float sv = a0 + a1, ssv = a0 * a0 + a1 * a1;
#pragma unroll
  for (int mm = 1; mm < 64; mm <<= 1) { sv += __shfl_xor(sv, mm); ssv += __shfl_xor(ssv, mm); }
  __shared__ float red[4][2];
  __shared__ float y[512];
  __shared__ float z[128];
  const int lane = e & 63, wv = e >> 6;
  if (lane == 0) { red[wv][0] = sv; red[wv][1] = ssv; }
  __syncthreads();
  const float S = red[0][0] + red[1][0] + red[2][0] + red[3][0];
  const float SS = red[0][1] + red[1][1] + red[2][1] + red[3][1];
  const float mu = S * (1.f / 512.f);
  const float rr = rsqrtf(SS * (1.f / 512.f) - mu * mu + 1e-5f);
  y[e] = (a0 - mu) * rr * png[e] + pnb[e];
  y[256 + e] = (a1 - mu) * rr * png[256 + e] + pnb[256 + e];
  __syncthreads();
  if (e < 128) {
    float a = f1b[e];
    for (int k = 0; k < 512; k++) a += y[k] * f1w[e * 512 + k];
    z[e] = fmaxf(a, 0.f);
  }
  __syncthreads();
  if (e < 64) {
    float p = z[e] * f2w[e] + z[e + 64] * f2w[e + 64];
#pragma unroll
    for (int mm = 1; mm < 64; mm <<= 1) p += __shfl_xor(p, mm);
    if (e == 0) outp[b] = p + f2b[0];
  }
}

// ---------------------------------------------------------------------------
// Host orchestration
// ---------------------------------------------------------------------------
extern "C" void kernel_launch(void* const* d_in, const int* in_sizes, int n_in,
                              void* d_out, int out_size, void* d_ws, size_t ws_size,
                              hipStream_t stream) {
  (void)in_sizes; (void)n_in; (void)out_size; (void)ws_size;
  const float* x      = (const float*)d_in[0];
  const float* c1w    = (const float*)d_in[1];
  const float* c1b    = (const float*)d_in[2];
  const float* bn1g   = (const float*)d_in[3];
  const float* bn1b   = (const float*)d_in[4];
  const float* c2w    = (const float*)d_in[5];
  const float* c2b    = (const float*)d_in[6];
  const float* bn2g   = (const float*)d_in[7];
  const float* bn2b   = (const float*)d_in[8];
  const float* g1W    = (const float*)d_in[9];
  const float* g1asrc = (const float*)d_in[10];
  const float* g1adst = (const float*)d_in[11];
  const float* g1adj  = (const float*)d_in[12];
  const float* n1g    = (const float*)d_in[13];
  const float* n1b    = (const float*)d_in[14];
  const float* g2W    = (const float*)d_in[15];
  const float* g2asrc = (const float*)d_in[16];
  const float* g2adst = (const float*)d_in[17];
  const float* g2adj  = (const float*)d_in[18];
  const float* n2g    = (const float*)d_in[19];
  const float* n2b    = (const float*)d_in[20];
  const float* l0fWih = (const float*)d_in[21];
  const float* l0fWhh = (const float*)d_in[22];
  const float* l0fbih = (const float*)d_in[23];
  const float* l0fbhh = (const float*)d_in[24];
  const float* l0rWih = (const float*)d_in[25];
  const float* l0rWhh = (const float*)d_in[26];
  const float* l0rbih = (const float*)d_in[27];
  const float* l0rbhh = (const float*)d_in[28];
  const float* l1fWih = (const float*)d_in[29];
  const float* l1fWhh = (const float*)d_in[30];
  const float* l1fbih = (const float*)d_in[31];
  const float* l1fbhh = (const float*)d_in[32];
  const float* l1rWih = (const float*)d_in[33];
  const float* l1rWhh = (const float*)d_in[34];
  const float* l1rbih = (const float*)d_in[35];
  const float* l1rbhh = (const float*)d_in[36];
  const float* wqkv   = (const float*)d_in[37];
  const float* bqkv   = (const float*)d_in[38];
  const float* wo     = (const float*)d_in[39];
  const float* bo     = (const float*)d_in[40];
  const float* ang    = (const float*)d_in[41];
  const float* anb    = (const float*)d_in[42];
  const float* png    = (const float*)d_in[43];
  const float* pnb    = (const float*)d_in[44];
  const float* f1w    = (const float*)d_in[45];
  const float* f1b    = (const float*)d_in[46];
  const float* f2w    = (const float*)d_in[47];
  const float* f2b    = (const float*)d_in[48];

  char* ws = (char*)d_ws;
  // Buffer overlay plan (total 223,395,840 B; lifetimes verified per stage):
  //  [0       , 67.1MB ) G0   (conv2 out) ........ then GAF (lstm gates f32)
  //  [67.1MB  , 134.2MB) C1   (conv1 out) ........ then low half of G1O,
  //                                               then OUT1 + QKV
  //  [67.1MB  , 201.3MB) G1O  (GAT out, (32768,2048) bf16, in-place gat2)
  //  [134.2MB , 218.1MB)      then AOb, PROJ, ATT
  //  [201.3MB , 218.1MB) WAUG1/2 (during conv+GAT) then OUT0 (lstm0 out)
  //  [218.1MB , 223.4MB) bf16 weights (persistent)
  auto G0   = (__hip_bfloat16*)(ws + 0L);
  auto C1   = (__hip_bfloat16*)(ws + 67108864L);
  auto G1O  = (__hip_bfloat16*)(ws + 67108864L);
  auto GAF  = (float*)(ws + 0L);
  auto OUT0 = (__hip_bfloat16*)(ws + 201326592L);
  auto OUT1 = (__hip_bfloat16*)(ws + 67108864L);
  auto QKV  = (__hip_bfloat16*)(ws + 83886080L);
  auto AOb  = (__hip_bfloat16*)(ws + 134217728L);
  auto PROJ = (float*)(ws + 150994944L);
  auto ATT  = (float*)(ws + 184549376L);
  // WAUG1/2 live in the OUT0 region (dead until lstm0 writes OUT0)
  auto WAUG1 = (__hip_bfloat16*)(ws + 201326592L);            // (144,64)
  auto WAUG2 = (__hip_bfloat16*)(ws + 201326592L + 20480L);   // (144,128)
  char* WB  = ws + 218103808L;
  auto WI0F  = (__hip_bfloat16*)(WB + 49152);    // (512,2048)
  auto WI0R  = (__hip_bfloat16*)(WB + 2146304);
  auto WI1F  = (__hip_bfloat16*)(WB + 4243456);  // (512,256)
  auto WI1R  = (__hip_bfloat16*)(WB + 4505600);
  auto WQKVb = (__hip_bfloat16*)(WB + 4767744);  // (768,256)
  auto WOb   = (__hip_bfloat16*)(WB + 5160960);  // (256,256)

  // --- weight prep (bf16; Wih/wqkv/wo are already (N,K) = B^T layout) ---
  gat_waug_k<<<36, 256, 0, stream>>>(g1W, g1asrc, g1adst, WAUG1, 64);
  gat_waug_k<<<72, 256, 0, stream>>>(g2W, g2asrc, g2adst, WAUG2, 128);
  cvt_bf16_k<<<4096, 256, 0, stream>>>(l0fWih, WI0F, 1048576);
  cvt_bf16_k<<<4096, 256, 0, stream>>>(l0rWih, WI0R, 1048576);
  cvt_bf16_k<<<512, 256, 0, stream>>>(l1fWih, WI1F, 131072);
  cvt_bf16_k<<<512, 256, 0, stream>>>(l1rWih, WI1R, 131072);
  cvt_bf16_k<<<768, 256, 0, stream>>>(wqkv, WQKVb, 196608);
  cvt_bf16_k<<<256, 256, 0, stream>>>(wo, WOb, 65536);

  // --- pipeline ---
  conv1_k<<<4096, 256, 0, stream>>>(x, c1w, c1b, bn1g, bn1b, C1);
  conv2_k<<<4096, 256, 0, stream>>>(C1, c2w, c2b, bn2g, bn2b, G0);
  gat_fused_k<64><<<32768, 128, 0, stream>>>(G0, WAUG1, g1adj, n1g, n1b, G1O);
  gat_fused_k<128><<<32768, 128, 0, stream>>>(G1O, WAUG2, g2adj, n2g, n2b, G1O);
  // LSTM layer 0 (dirs serialized on one gate buffer)
  gemm_bt<false><<<dim3(4, 256), 256, 0, stream>>>(G1O, WI0F, GAF, nullptr, 32768, 512, 2048);
  lstm_mfma_k<<<128, 512, 0, stream>>>(GAF, l0fWhh, l0fbih, l0fbhh, OUT0, 0, 0);
  gemm_bt<false><<<dim3(4, 256), 256, 0, stream>>>(G1O, WI0R, GAF, nullptr, 32768, 512, 2048);
  lstm_mfma_k<<<128, 512, 0, stream>>>(GAF, l0rWhh, l0rbih, l0rbhh, OUT0, 1, 128);
  // LSTM layer 1
  gemm_bt<false><<<dim3(4, 256), 256, 0, stream>>>(OUT0, WI1F, GAF, nullptr, 32768, 512, 256);
  lstm_mfma_k<<<128, 512, 0, stream>>>(GAF, l1fWhh, l1fbih, l1fbhh, OUT1, 0, 0);
  gemm_bt<false><<<dim3(4, 256), 256, 0, stream>>>(OUT0, WI1R, GAF, nullptr, 32768, 512, 256);
  lstm_mfma_k<<<128, 512, 0, stream>>>(GAF, l1rWhh, l1rbih, l1rbhh, OUT1, 1, 128);
  // MHA block
  gemm_bt<true><<<dim3(6, 256), 256, 0, stream>>>(OUT1, WQKVb, QKV, bqkv, 32768, 768, 256);
  mha_k<<<1024, 256, 0, stream>>>(QKV, AOb);
  gemm_bt<false><<<dim3(2, 256), 256, 0, stream>>>(AOb, WOb, PROJ, bo, 32768, 256, 256);
  resid_ln_k<<<32768, 256, 0, stream>>>(PROJ, OUT1, ang, anb, ATT);
  pool_k<<<256, 256, 0, stream>>>(ATT, png, pnb, f1w, f1b, f2w, f2b, (float*)d_out);
}

// Round 7
// 1448.442 us; speedup vs baseline: 2.6494x; 1.1779x over previous
//
#include <hip/hip_runtime.h>
#include <hip/hip_bf16.h>
#include <stdint.h>

// ---------------------------------------------------------------------------
// M6_GraphBiLSTM: conv1 -> conv2 -> GAT x2 -> BiLSTM x2 -> MHA -> pool -> FC
// Round 7: conv2 rebuilt as MFMA conv-GEMM (R6 profile: conv2_k 307us,
// VALUBusy 85%, MfmaUtil 0 -- scalar ds_read bound). K ordered (tap, ic),
// weights register-resident, XOR-swizzled LDS input (4-way residual).
// Also: bijective XCD swizzle in gemm_bt (gates GEMM re-fetched A 2.3x).
// Shapes: B=256, C=16, T=256, TC=128, H=128, HEADS=4, D=32, E=256
// ---------------------------------------------------------------------------

typedef __attribute__((ext_vector_type(8))) short bh8;    // 8 x bf16 (4 VGPR)
typedef __attribute__((ext_vector_type(4))) float f32x4;  // MFMA accumulator

__device__ __forceinline__ float bfu2f(unsigned short u) {
  union { unsigned u; float f; } x; x.u = ((unsigned)u) << 16; return x.f;
}
__device__ __forceinline__ unsigned short f2bfu(float f) {
  __hip_bfloat16 h = __float2bfloat16(f);
  return *reinterpret_cast<unsigned short*>(&h);
}
__device__ __forceinline__ float geluf(float v) {
  return 0.5f * v * (1.f + erff(v * 0.70710678118f));
}
__device__ __forceinline__ float sigmoidf_(float x) { return 1.f / (1.f + __expf(-x)); }
__device__ __forceinline__ float tanh_(float x) {
  x = fminf(fmaxf(x, -30.f), 30.f);
  float e = __expf(2.f * x);
  return (e - 1.f) / (e + 1.f);
}

// async global->LDS, 16B per lane; LDS dest = wave-uniform base + lane*16
__device__ __forceinline__ void g2l16(const void* g, void* l) {
  __builtin_amdgcn_global_load_lds(
      (const __attribute__((address_space(1))) unsigned int*)g,
      (__attribute__((address_space(3))) unsigned int*)l, 16, 0, 0);
}

// ---------------------------------------------------------------------------
// Weight prep
// ---------------------------------------------------------------------------
__global__ __launch_bounds__(256) void cvt_bf16_k(const float* __restrict__ s,
                                                  __hip_bfloat16* __restrict__ d, int n) {
  int i = blockIdx.x * 256 + threadIdx.x;
  if (i < n) d[i] = __float2bfloat16(s[i]);
}

// Augmented GAT weight: waug (144 rows x K) bf16.
__global__ __launch_bounds__(256)
void gat_waug_k(const float* __restrict__ W, const float* __restrict__ asrc,
                const float* __restrict__ adst, __hip_bfloat16* __restrict__ waug,
                int K) {
  int idx = blockIdx.x * 256 + threadIdx.x;
  if (idx >= 144 * K) return;
  const int row = idx / K, k = idx % K;
  float v = 0.f;
  if (row < 128) {
    v = W[k * 128 + row];
  } else if (row < 136) {
    const int h = (row - 128) & 3;
    const float* av = (row < 132) ? asrc : adst;
    for (int d = 0; d < 32; d++) v += W[k * 128 + h * 32 + d] * av[h * 32 + d];
  }
  waug[row * K + k] = __float2bfloat16(v);
}

// conv2 weight reorder: wc2[oc][kt*32+ic] = w2[oc][ic][kt] bf16, + BN fold
__global__ __launch_bounds__(256)
void conv2w_k(const float* __restrict__ w2, const float* __restrict__ b2,
              const float* __restrict__ g2, const float* __restrict__ bb2,
              __hip_bfloat16* __restrict__ wc2, float* __restrict__ sc,
              float* __restrict__ sh) {
  const int tid = blockIdx.x * 256 + threadIdx.x;
  if (tid < 64 * 160) {
    const int oc = tid / 160, k = tid % 160;
    const int kt = k >> 5, ic = k & 31;
    wc2[tid] = __float2bfloat16(w2[oc * 160 + ic * 5 + kt]);
  }
  if (tid < 64) { sc[tid] = g2[tid]; sh[tid] = b2[tid] * g2[tid] + bb2[tid]; }
}

// ---------------------------------------------------------------------------
// conv1 (k=7, pad 3) + BN + GELU.  x:(4096,256) f32 -> c1:(4096,32,256) bf16
// ---------------------------------------------------------------------------
__global__ __launch_bounds__(256)
void conv1_k(const float* __restrict__ x, const float* __restrict__ w,
             const float* __restrict__ b, const float* __restrict__ g,
             const float* __restrict__ bb, __hip_bfloat16* __restrict__ c1) {
  __shared__ float xs[264];
  const int nn = blockIdx.x, t = threadIdx.x;
  xs[3 + t] = x[nn * 256 + t];
  if (t < 3) { xs[t] = 0.f; xs[259 + t] = 0.f; }
  __syncthreads();
  for (int oc = 0; oc < 32; oc++) {
    float acc = 0.f;
#pragma unroll
    for (int k = 0; k < 7; k++) acc += xs[t + k] * w[oc * 7 + k];
    float v = (acc + b[oc]) * g[oc] + bb[oc];
    c1[(nn * 32 + oc) * 256 + t] = __float2bfloat16(geluf(v));
  }
}

// ---------------------------------------------------------------------------
// conv2 via MFMA. Per block nn: out[oc 64][to 128] = sum_{kt,ic} wc2 * in.
// A = weights (M=oc, regs), B = input (N=to, swizzled LDS). K=160 = 5kt x 32ic.
// 4 waves, wave wv owns to in [wv*32, wv*32+32) (2 n-frags). BN+GELU epilogue.
// Output layout: g0[((b*128+to)*16 + c)*64 + oc], nn = b*16+c.
// ---------------------------------------------------------------------------
__global__ __launch_bounds__(256)
void conv2_mfma_k(const __hip_bfloat16* __restrict__ c1,
                  const __hip_bfloat16* __restrict__ wc2,
                  const float* __restrict__ scale, const float* __restrict__ shift,
                  __hip_bfloat16* __restrict__ g0) {
  const int nn = blockIdx.x, tid = threadIdx.x;
  const int lane = tid & 63, wv = tid >> 6;
  const int cl = lane & 15, hi = lane >> 4;
  __shared__ __align__(16) __hip_bfloat16 L[260 * 32];  // [col][ic] swizzled
  __shared__ float sc_s[64], sh_s[64];
  // zero pad cols {0,1,258,259}
  if (tid < 64) {
    const int pcol = (tid >> 4) < 2 ? (tid >> 4) : 256 + (tid >> 4);
    ((unsigned*)L)[pcol * 16 + (tid & 15)] = 0u;
  }
  if (tid >= 64 && tid < 128) { sc_s[tid - 64] = scale[tid - 64]; sh_s[tid - 64] = shift[tid - 64]; }
  // stage input: thread (ic2 = tid&15 -> ic pair, tg = tid>>4 -> 16 t's)
  {
    const int ic2 = tid & 15, tg = tid >> 4;
    const __hip_bfloat16* r0 = c1 + ((long)nn * 32 + 2 * ic2) * 256 + tg * 16;
    const bh8 v0a = *(const bh8*)(r0);
    const bh8 v0b = *(const bh8*)(r0 + 8);
    const bh8 v1a = *(const bh8*)(r0 + 256);
    const bh8 v1b = *(const bh8*)(r0 + 264);
    const int g = ic2 >> 2;  // = ic>>3 for ic=2*ic2
#pragma unroll
    for (int e = 0; e < 16; e++) {
      const int col = tg * 16 + e + 2;
      const unsigned lo = (unsigned)(unsigned short)((e < 8) ? v0a[e] : v0b[e - 8]);
      const unsigned hh = (unsigned)(unsigned short)((e < 8) ? v1a[e] : v1b[e - 8]);
      const int pos = (g ^ ((col >> 1) & 3)) * 8 + ((2 * ic2) & 7);
      *(unsigned*)((char*)L + col * 64 + pos * 2) = lo | (hh << 16);
    }
  }
  // weights -> registers: af[mt][kt], row oc = mt*16+cl, k = kt*32+hi*8..+8
  bh8 af[4][5];
#pragma unroll
  for (int mt = 0; mt < 4; mt++)
#pragma unroll
    for (int kt = 0; kt < 5; kt++)
      af[mt][kt] = *(const bh8*)(wc2 + (mt * 16 + cl) * 160 + kt * 32 + hi * 8);
  __syncthreads();
  f32x4 acc[4][2] = {};
#pragma unroll
  for (int nf = 0; nf < 2; nf++) {
    const int to = wv * 32 + nf * 16 + cl;
#pragma unroll
    for (int kt = 0; kt < 5; kt++) {
      const int col = 2 * to + kt;
      const bh8 bf = *(const bh8*)((const char*)L + col * 64 + ((hi ^ ((col >> 1) & 3)) * 8) * 2);
#pragma unroll
      for (int mt = 0; mt < 4; mt++)
        acc[mt][nf] = __builtin_amdgcn_mfma_f32_16x16x32_bf16(af[mt][kt], bf, acc[mt][nf], 0, 0, 0);
    }
  }
  const int b = nn >> 4, c = nn & 15;
#pragma unroll
  for (int nf = 0; nf < 2; nf++) {
    const int to = wv * 32 + nf * 16 + cl;
    __hip_bfloat16* outb = g0 + ((long)(b * 128 + to) * 16 + c) * 64;
#pragma unroll
    for (int mt = 0; mt < 4; mt++) {
      ushort4 pk;
      unsigned short* pp = (unsigned short*)&pk;
#pragma unroll
      for (int r = 0; r < 4; r++) {
        const int oc = mt * 16 + hi * 4 + r;
        pp[r] = f2bfu(geluf(acc[mt][nf][r] * sc_s[oc] + sh_s[oc]));
      }
      *(ushort4*)(outb + mt * 16 + hi * 4) = pk;
    }
  }
}

// ---------------------------------------------------------------------------
// bf16 MFMA GEMM:  C(M,N) = A(M,K) @ B(N,K)^T  (+bias[N]), m97 structure,
// with bijective XCD-aware tile swizzle (m204).
// ---------------------------------------------------------------------------
template <bool OUT_BF16>
__global__ __launch_bounds__(256)
void gemm_bt(const __hip_bfloat16* __restrict__ A, const __hip_bfloat16* __restrict__ Bm,
             void* __restrict__ Cout, const float* __restrict__ bias,
             int M, int N, int K) {
  __shared__ __align__(16) __hip_bfloat16 sA[128 * 32];
  __shared__ __align__(16) __hip_bfloat16 sB[128 * 32];
  const int tid = threadIdx.x;
  const int lane = tid & 63, wv = tid >> 6;
  const int wr = wv >> 1, wc = wv & 1;
  // XCD swizzle: dispatch-consecutive chunks of nwg/8 land on one XCD
  int fid = blockIdx.y * gridDim.x + blockIdx.x;
  {
    const int nwg = gridDim.x * gridDim.y;
    const int q = nwg >> 3, r = nwg & 7;
    const int xcd = fid & 7, off = fid >> 3;
    fid = (xcd < r ? xcd * (q + 1) : r * (q + 1) + (xcd - r) * q) + off;
  }
  const long m0 = (long)(fid / gridDim.x) * 128;
  const long n0 = (long)(fid % gridDim.x) * 128;
  // staging: 512 16B-chunks per matrix; this thread owns 2 (q=0,1)
  const int sa0 = wv * 128 + lane, sa1 = wv * 128 + 64 + lane;
  const int ra0 = sa0 >> 2, ca0 = sa0 & 3;
  const int ra1 = sa1 >> 2, ca1 = sa1 & 3;
  const __hip_bfloat16* a0 = A + (m0 + ra0) * K + ca0 * 8;
  const __hip_bfloat16* a1 = A + (m0 + ra1) * K + ca1 * 8;
  const __hip_bfloat16* b0 = Bm + (n0 + ra0) * K + ca0 * 8;
  const __hip_bfloat16* b1 = Bm + (n0 + ra1) * K + ca1 * 8;
  char* lA0 = (char*)sA + wv * 2048;
  char* lA1 = (char*)sA + wv * 2048 + 1024;
  char* lB0 = (char*)sB + wv * 2048;
  char* lB1 = (char*)sB + wv * 2048 + 1024;
  f32x4 acc[4][4] = {};
  const int rfA = wr * 64 + (lane & 15);
  const int rfB = wc * 64 + (lane & 15);
  const int kf = (lane >> 4) * 8;
  for (int kt = 0; kt < K; kt += 32) {
    __syncthreads();
    g2l16(a0 + kt, lA0);
    g2l16(a1 + kt, lA1);
    g2l16(b0 + kt, lB0);
    g2l16(b1 + kt, lB1);
    __syncthreads();
    bh8 af[4], bf[4];
#pragma unroll
    for (int m = 0; m < 4; m++) af[m] = *(const bh8*)(sA + (rfA + m * 16) * 32 + kf);
#pragma unroll
    for (int n = 0; n < 4; n++) bf[n] = *(const bh8*)(sB + (rfB + n * 16) * 32 + kf);
#pragma unroll
    for (int m = 0; m < 4; m++)
#pragma unroll
      for (int n = 0; n < 4; n++)
        acc[m][n] = __builtin_amdgcn_mfma_f32_16x16x32_bf16(af[m], bf[n], acc[m][n], 0, 0, 0);
  }
#pragma unroll
  for (int n = 0; n < 4; n++) {
    const long col = n0 + wc * 64 + n * 16 + (lane & 15);
    const float bv = bias ? bias[col] : 0.f;
#pragma unroll
    for (int m = 0; m < 4; m++) {
      const long row0 = m0 + wr * 64 + m * 16 + ((lane >> 4) * 4);
#pragma unroll
      for (int r = 0; r < 4; r++) {
        float v = acc[m][n][r] + bv;
        if (OUT_BF16)
          ((__hip_bfloat16*)Cout)[(row0 + r) * N + col] = __float2bfloat16(v);
        else
          ((float*)Cout)[(row0 + r) * N + col] = v;
      }
    }
  }
}

// ---------------------------------------------------------------------------
// Fused GAT layer v2 (per n of 32768): [h | es | ed] = h_in(16,K) @ WAUG via
// MFMA, then softmax-attn, ReLU, LayerNorm(128). In-place safe.
// ---------------------------------------------------------------------------
template <int K>
__global__ __launch_bounds__(128)
void gat_fused_k(const __hip_bfloat16* __restrict__ hin,
                 const __hip_bfloat16* __restrict__ waug,
                 const float* __restrict__ adj, const float* __restrict__ lng,
                 const float* __restrict__ lnb, __hip_bfloat16* __restrict__ outp) {
  const long n = blockIdx.x;
  const int f = threadIdx.x;          // 0..127, f = head*32 + d
  const int lane = f & 63, wv = f >> 6;
  const int head = f >> 5;
  __shared__ float hs[16][132];       // projected h (then reused for o)
  __shared__ float adj_s[16][16];
  __shared__ float es_s[16][4], ed_s[16][4];
  __shared__ float a_s[16][65];       // stride 65: conflict-free
  __shared__ float mean_s[16], rs_s[16];
  const __hip_bfloat16* An = hin + n * 16 * K;
  const int ar = lane & 15, hi = lane >> 4, ak = hi * 8;
  f32x4 pacc[4] = {};
  f32x4 pe = {};
  for (int kt = 0; kt < K; kt += 32) {
    const bh8 af = *(const bh8*)(An + ar * K + kt + ak);
#pragma unroll
    for (int s = 0; s < 4; s++) {
      const bh8 bf = *(const bh8*)(waug + (wv * 64 + s * 16 + ar) * K + kt + ak);
      pacc[s] = __builtin_amdgcn_mfma_f32_16x16x32_bf16(af, bf, pacc[s], 0, 0, 0);
    }
    if (wv == 0) {
      const bh8 be = *(const bh8*)(waug + (128 + ar) * K + kt + ak);
      pe = __builtin_amdgcn_mfma_f32_16x16x32_bf16(af, be, pe, 0, 0, 0);
    }
  }
  for (int idx = f; idx < 256; idx += 128) adj_s[idx >> 4][idx & 15] = adj[idx];
#pragma unroll
  for (int s = 0; s < 4; s++)
#pragma unroll
    for (int r = 0; r < 4; r++)
      hs[hi * 4 + r][wv * 64 + s * 16 + ar] = pacc[s][r];
  if (wv == 0 && ar < 8) {
#pragma unroll
    for (int r = 0; r < 4; r++) {
      const int c = hi * 4 + r;
      if (ar < 4) es_s[c][ar] = pe[r];
      else        ed_s[c][ar - 4] = pe[r];
    }
  }
  __syncthreads();
  if (f < 64) {
    const int i = f >> 2, hd = f & 3;
    float ev[16], mx = -1e30f;
#pragma unroll
    for (int j = 0; j < 16; j++) {
      float e = es_s[i][hd] + ed_s[j][hd];
      e = (e > 0.f ? e : 0.2f * e) + adj_s[i][j];
      ev[j] = e; mx = fmaxf(mx, e);
    }
    float sm = 0.f;
#pragma unroll
    for (int j = 0; j < 16; j++) { ev[j] = __expf(ev[j] - mx); sm += ev[j]; }
    const float inv = 1.f / sm;
#pragma unroll
    for (int j = 0; j < 16; j++) a_s[i][j * 4 + hd] = ev[j] * inv;
  }
  __syncthreads();
  float hv[16];
#pragma unroll
  for (int c = 0; c < 16; c++) hv[c] = hs[c][f];
  __syncthreads();
  float o[16];
#pragma unroll
  for (int i = 0; i < 16; i++) {
    float acc = 0.f;
#pragma unroll
    for (int j = 0; j < 16; j++) acc += a_s[i][j * 4 + head] * hv[j];
    acc = fmaxf(acc, 0.f);
    o[i] = acc;
    hs[i][f] = acc;
  }
  __syncthreads();
  {
    const int i = f >> 3, g = f & 7;
    float s = 0.f, ss = 0.f;
#pragma unroll
    for (int q = 0; q < 16; q++) {
      const float v = hs[i][g * 16 + q];
      s += v; ss += v * v;
    }
#pragma unroll
    for (int m = 1; m < 8; m <<= 1) { s += __shfl_xor(s, m); ss += __shfl_xor(ss, m); }
    if (g == 0) {
      const float mean = s * (1.f / 128.f);
      const float var = ss * (1.f / 128.f) - mean * mean;
      mean_s[i] = mean;
      rs_s[i] = rsqrtf(var + 1e-5f);
    }
  }
  __syncthreads();
  const float gw = lng[f], gb = lnb[f];
#pragma unroll
  for (int i = 0; i < 16; i++)
    outp[(n * 16 + i) * 128 + f] = __float2bfloat16((o[i] - mean_s[i]) * rs_s[i] * gw + gb);
}

// ---------------------------------------------------------------------------
// BiLSTM recurrence via MFMA (see R5 notes). 128 blocks, 8 waves, Whh in regs.
// ---------------------------------------------------------------------------
__global__ __launch_bounds__(512)
void lstm_mfma_k(const float* __restrict__ gates, const float* __restrict__ whh,
                 const float* __restrict__ bih, const float* __restrict__ bhh,
                 __hip_bfloat16* __restrict__ outp, const int dir, const int colOff) {
  const int chunk = blockIdx.x;
  const int tid = threadIdx.x;
  const int lane = tid & 63, w = tid >> 6;
  const int cl = lane & 15, hi = lane >> 4;
  __shared__ __align__(16) __hip_bfloat16 h_frag[2048];
  __shared__ float g_lds[2][520];
  for (int idx = tid; idx < 1024; idx += 512) ((unsigned*)h_frag)[idx] = 0u;
  bh8 bfr[4][4];
#pragma unroll
  for (int n = 0; n < 4; n++)
#pragma unroll
    for (int kt = 0; kt < 4; kt++) {
      const float* wp = whh + (w * 64 + n * 16 + cl) * 128 + kt * 32 + hi * 8;
      const float4 lo = *(const float4*)wp;
      const float4 hv = *(const float4*)(wp + 4);
      bh8 r;
      r[0] = (short)f2bfu(lo.x); r[1] = (short)f2bfu(lo.y);
      r[2] = (short)f2bfu(lo.z); r[3] = (short)f2bfu(lo.w);
      r[4] = (short)f2bfu(hv.x); r[5] = (short)f2bfu(hv.y);
      r[6] = (short)f2bfu(hv.z); r[7] = (short)f2bfu(hv.w);
      bfr[n][kt] = r;
    }
  float bs[4];
#pragma unroll
  for (int n = 0; n < 4; n++)
    bs[n] = bih[w * 64 + n * 16 + cl] + bhh[w * 64 + n * 16 + cl];
  const int ub = tid >> 7, uj = tid & 127;
  float c_st = 0.f;
  __syncthreads();
  for (int s = 0; s < 128; s++) {
    const int t = dir ? (127 - s) : s;
    float gin[4][2];
    if (hi == 0) {
#pragma unroll
      for (int n = 0; n < 4; n++)
#pragma unroll
        for (int r = 0; r < 2; r++)
          gin[n][r] = gates[((long)(chunk * 2 + r) * 128 + t) * 512 + w * 64 + n * 16 + cl];
    }
    bh8 af[4];
#pragma unroll
    for (int kt = 0; kt < 4; kt++)
      af[kt] = *(const bh8*)(h_frag + kt * 512 + lane * 8);
    f32x4 acc[4] = {};
#pragma unroll
    for (int n = 0; n < 4; n++)
#pragma unroll
      for (int kt = 0; kt < 4; kt++)
        acc[n] = __builtin_amdgcn_mfma_f32_16x16x32_bf16(af[kt], bfr[n][kt], acc[n], 0, 0, 0);
    if (hi == 0) {
#pragma unroll
      for (int n = 0; n < 4; n++)
#pragma unroll
        for (int r = 0; r < 2; r++)
          g_lds[r][w * 64 + n * 16 + cl] = acc[n][r] + gin[n][r] + bs[n];
    }
    __syncthreads();
    if (tid < 256) {
      const float gi = sigmoidf_(g_lds[ub][uj]);
      const float gf = sigmoidf_(g_lds[ub][uj + 128]);
      const float gg = tanh_(g_lds[ub][uj + 256]);
      const float go = sigmoidf_(g_lds[ub][uj + 384]);
      const float c = gf * c_st + gi * gg;
      c_st = c;
      const float hh = go * tanh_(c);
      h_frag[(uj >> 5) * 512 + ((uj >> 3) & 3) * 128 + ub * 8 + (uj & 7)] =
          __float2bfloat16(hh);
      outp[((long)(chunk * 2 + ub) * 128 + t) * 256 + colOff + uj] = __float2bfloat16(hh);
    }
    __syncthreads();
  }
}

// ---------------------------------------------------------------------------
// MHA attention core: per (b, head) block. qkv bf16 (32768,768) -> ao bf16
// ---------------------------------------------------------------------------
#define DOT8T(Q, O, KV)                                                        \
  (Q[(O) + 0] * bfu2f((unsigned short)(KV)[0]) +                               \
   Q[(O) + 1] * bfu2f((unsigned short)(KV)[1]) +                               \
   Q[(O) + 2] * bfu2f((unsigned short)(KV)[2]) +                               \
   Q[(O) + 3] * bfu2f((unsigned short)(KV)[3]) +                               \
   Q[(O) + 4] * bfu2f((unsigned short)(KV)[4]) +                               \
   Q[(O) + 5] * bfu2f((unsigned short)(KV)[5]) +                               \
   Q[(O) + 6] * bfu2f((unsigned short)(KV)[6]) +                               \
   Q[(O) + 7] * bfu2f((unsigned short)(KV)[7]))

__global__ __launch_bounds__(256)
void mha_k(const __hip_bfloat16* __restrict__ qkv, __hip_bfloat16* __restrict__ ao) {
  const int bh = blockIdx.x;
  const int b = bh >> 2, hd = bh & 3;
  const int tid = threadIdx.x;
  __shared__ __align__(16) __hip_bfloat16 ks[128 * 68];
  __shared__ __align__(16) __hip_bfloat16 vs[128 * 68];
  __shared__ __align__(16) char xreg[33792];
  __shared__ float mx_s[2][128], sm_s[2][128];
  const long base = (long)b * 128 * 768 + hd * 64;
  for (int idx = tid; idx < 3072; idx += 256) {
    const int mm = idx >> 10, cc = idx & 1023;
    const int t = cc >> 3, c8 = cc & 7;
    const bh8 val = *(const bh8*)(qkv + base + (long)t * 768 + mm * 256 + c8 * 8);
    __hip_bfloat16* dst = (mm == 0) ? (__hip_bfloat16*)xreg : (mm == 1 ? ks : vs);
    *(bh8*)(dst + t * 68 + c8 * 8) = val;
  }
  __syncthreads();
  const int i = tid & 127;
  const int jh = tid >> 7;
  float qf[64];
#pragma unroll
  for (int kk = 0; kk < 8; kk++) {
    const bh8 v8 = *(const bh8*)((const __hip_bfloat16*)xreg + i * 68 + kk * 8);
#pragma unroll
    for (int e = 0; e < 8; e++) qf[kk * 8 + e] = bfu2f((unsigned short)v8[e]);
  }
  float s[64];
#pragma unroll
  for (int jo = 0; jo < 64; jo++) {
    const int j = jh * 64 + jo;
    float acc = 0.f;
#pragma unroll
    for (int kk = 0; kk < 8; kk++) {
      const bh8 kv = *(const bh8*)(ks + j * 68 + kk * 8);
      acc += DOT8T(qf, kk * 8, kv);
    }
    s[jo] = acc * 0.125f;
  }
  float mx = -1e30f;
#pragma unroll
  for (int jo = 0; jo < 64; jo++) mx = fmaxf(mx, s[jo]);
  mx_s[jh][i] = mx;
  __syncthreads();
  const float m = fmaxf(mx_s[0][i], mx_s[1][i]);
  float sum = 0.f;
#pragma unroll
  for (int jo = 0; jo < 64; jo++) { s[jo] = __expf(s[jo] - m); sum += s[jo]; }
  sm_s[jh][i] = sum;
  __syncthreads();
  const float inv = 1.f / (sm_s[0][i] + sm_s[1][i]);
  __hip_bfloat16* P = (__hip_bfloat16*)xreg;
#pragma unroll
  for (int jo = 0; jo < 64; jo += 2) {
    const unsigned u = (unsigned)f2bfu(s[jo] * inv) | ((unsigned)f2bfu(s[jo + 1] * inv) << 16);
    *(unsigned*)(P + i * 132 + jh * 64 + jo) = u;
  }
  __syncthreads();
  const int dh = jh;
  float acc[32];
#pragma unroll
  for (int e = 0; e < 32; e++) acc[e] = 0.f;
  for (int j = 0; j < 128; j++) {
    const float p = bfu2f(*(const unsigned short*)(P + i * 132 + j));
#pragma unroll
    for (int kk = 0; kk < 4; kk++) {
      const bh8 vv = *(const bh8*)(vs + j * 68 + dh * 32 + kk * 8);
      acc[kk * 8 + 0] += p * bfu2f((unsigned short)vv[0]);
      acc[kk * 8 + 1] += p * bfu2f((unsigned short)vv[1]);
      acc[kk * 8 + 2] += p * bfu2f((unsigned short)vv[2]);
      acc[kk * 8 + 3] += p * bfu2f((unsigned short)vv[3]);
      acc[kk * 8 + 4] += p * bfu2f((unsigned short)vv[4]);
      acc[kk * 8 + 5] += p * bfu2f((unsigned short)vv[5]);
      acc[kk * 8 + 6] += p * bfu2f((unsigned short)vv[6]);
      acc[kk * 8 + 7] += p * bfu2f((unsigned short)vv[7]);
    }
  }
  const long ob = ((long)b * 128 + i) * 256 + hd * 64 + dh * 32;
#pragma unroll
  for (int kk = 0; kk < 16; kk++) {
    const unsigned u = (unsigned)f2bfu(acc[2 * kk]) | ((unsigned)f2bfu(acc[2 * kk + 1]) << 16);
    *(unsigned*)(ao + ob + kk * 2) = u;
  }
}

// ---------------------------------------------------------------------------
// residual + LayerNorm(256)
// ---------------------------------------------------------------------------
__global__ __launch_bounds__(256)
void resid_ln_k(const float* __restrict__ proj, const __hip_bfloat16* __restrict__ o,
                const float* __restrict__ g, const float* __restrict__ bb,
                float* __restrict__ att) {
  const long m = blockIdx.x;
  const int t = threadIdx.x;
  const float v = proj[m * 256 + t] + __bfloat162float(o[m * 256 + t]);
  float sv = v, ssv = v * v;
#pragma unroll
  for (int mm = 1; mm < 64; mm <<= 1) { sv += __shfl_xor(sv, mm); ssv += __shfl_xor(ssv, mm); }
  __shared__ float red[4][2];
  const int lane = t & 63, wv = t >> 6;
  if (lane == 0) { red[wv][0] = sv; red[wv][1] = ssv; }
  __syncthreads();
  const float S = red[0][0] + red[1][0] + red[2][0] + red[3][0];
  const float SS = red[0][1] + red[1][1] + red[2][1] + red[3][1];
  const float mu = S * (1.f / 256.f);
  const float rr = rsqrtf(SS * (1.f / 256.f) - mu * mu + 1e-5f);
  att[m * 256 + t] = (v - mu) * rr * g[t] + bb[t];
}

// ---------------------------------------------------------------------------
// pooling (mean+max over t) -> LN(512) -> fc1+relu -> fc2 -> d_out[b]
// ---------------------------------------------------------------------------
__global__ __launch_bounds__(256)
void pool_k(const float* __restrict__ att, const float* __restrict__ png,
            const float* __restrict__ pnb, const float* __restrict__ f1w,
            const float* __restrict__ f1b, const float* __restrict__ f2w,
            const float* __restrict__ f2b, float* __restrict__ outp) {
  const int b = blockIdx.x, e = threadIdx.x;
  float sum = 0.f, mx = -1e30f;
  for (int t = 0; t < 128; t++) {
    const float v = att[((long)b * 128 + t) * 256 + e];
    sum += v; mx = fmaxf(mx, v);
  }
  const float a0 = sum * (1.f / 128.f), a1 = mx;
  float sv = a0 + a1, ssv = a0 * a0 + a1 * a1;
#pragma unroll
  for (int mm = 1; mm < 64; mm <<= 1) { sv += __shfl_xor(sv, mm); ssv += __shfl_xor(ssv, mm); }
  __shared__ float red[4][2];
  __shared__ float y[512];
  __shared__ float z[128];
  const int lane = e & 63, wv = e >> 6;
  if (lane == 0) { red[wv][0] = sv; red[wv][1] = ssv; }
  __syncthreads();
  const float S = red[0][0] + red[1][0] + red[2][0] + red[3][0];
  const float SS = red[0][1] + red[1][1] + red[2][1] + red[3][1];
  const float mu = S * (1.f / 512.f);
  const float rr = rsqrtf(SS * (1.f / 512.f) - mu * mu + 1e-5f);
  y[e] = (a0 - mu) * rr * png[e] + pnb[e];
  y[256 + e] = (a1 - mu) * rr * png[256 + e] + pnb[256 + e];
  __syncthreads();
  if (e < 128) {
    float a = f1b[e];
    for (int k = 0; k < 512; k++) a += y[k] * f1w[e * 512 + k];
    z[e] = fmaxf(a, 0.f);
  }
  __syncthreads();
  if (e < 64) {
    float p = z[e] * f2w[e] + z[e + 64] * f2w[e + 64];
#pragma unroll
    for (int mm = 1; mm < 64; mm <<= 1) p += __shfl_xor(p, mm);
    if (e == 0) outp[b] = p + f2b[0];
  }
}

// ---------------------------------------------------------------------------
// Host orchestration
// ---------------------------------------------------------------------------
extern "C" void kernel_launch(void* const* d_in, const int* in_sizes, int n_in,
                              void* d_out, int out_size, void* d_ws, size_t ws_size,
                              hipStream_t stream) {
  (void)in_sizes; (void)n_in; (void)out_size; (void)ws_size;
  const float* x      = (const float*)d_in[0];
  const float* c1w    = (const float*)d_in[1];
  const float* c1b    = (const float*)d_in[2];
  const float* bn1g   = (const float*)d_in[3];
  const float* bn1b   = (const float*)d_in[4];
  const float* c2w    = (const float*)d_in[5];
  const float* c2b    = (const float*)d_in[6];
  const float* bn2g   = (const float*)d_in[7];
  const float* bn2b   = (const float*)d_in[8];
  const float* g1W    = (const float*)d_in[9];
  const float* g1asrc = (const float*)d_in[10];
  const float* g1adst = (const float*)d_in[11];
  const float* g1adj  = (const float*)d_in[12];
  const float* n1g    = (const float*)d_in[13];
  const float* n1b    = (const float*)d_in[14];
  const float* g2W    = (const float*)d_in[15];
  const float* g2asrc = (const float*)d_in[16];
  const float* g2adst = (const float*)d_in[17];
  const float* g2adj  = (const float*)d_in[18];
  const float* n2g    = (const float*)d_in[19];
  const float* n2b    = (const float*)d_in[20];
  const float* l0fWih = (const float*)d_in[21];
  const float* l0fWhh = (const float*)d_in[22];
  const float* l0fbih = (const float*)d_in[23];
  const float* l0fbhh = (const float*)d_in[24];
  const float* l0rWih = (const float*)d_in[25];
  const float* l0rWhh = (const float*)d_in[26];
  const float* l0rbih = (const float*)d_in[27];
  const float* l0rbhh = (const float*)d_in[28];
  const float* l1fWih = (const float*)d_in[29];
  const float* l1fWhh = (const float*)d_in[30];
  const float* l1fbih = (const float*)d_in[31];
  const float* l1fbhh = (const float*)d_in[32];
  const float* l1rWih = (const float*)d_in[33];
  const float* l1rWhh = (const float*)d_in[34];
  const float* l1rbih = (const float*)d_in[35];
  const float* l1rbhh = (const float*)d_in[36];
  const float* wqkv   = (const float*)d_in[37];
  const float* bqkv   = (const float*)d_in[38];
  const float* wo     = (const float*)d_in[39];
  const float* bo     = (const float*)d_in[40];
  const float* ang    = (const float*)d_in[41];
  const float* anb    = (const float*)d_in[42];
  const float* png    = (const float*)d_in[43];
  const float* pnb    = (const float*)d_in[44];
  const float* f1w    = (const float*)d_in[45];
  const float* f1b    = (const float*)d_in[46];
  const float* f2w    = (const float*)d_in[47];
  const float* f2b    = (const float*)d_in[48];

  char* ws = (char*)d_ws;
  // Buffer overlay plan (total 223,395,840 B; lifetimes verified per stage):
  //  [0       , 67.1MB ) G0   (conv2 out) ........ then GAF (lstm gates f32)
  //  [67.1MB  , 134.2MB) C1   (conv1 out) ........ then low half of G1O,
  //                                               then OUT1 + QKV
  //  [67.1MB  , 201.3MB) G1O  (GAT out) ... then AOb, PROJ, ATT
  //  [201.3MB , 218.1MB) WAUG1/2 (during conv+GAT) then OUT0 (lstm0 out)
  //  [218.1MB , 223.4MB) bf16 weights (persistent; wc2/sc/sh in first 49KB)
  auto G0   = (__hip_bfloat16*)(ws + 0L);
  auto C1   = (__hip_bfloat16*)(ws + 67108864L);
  auto G1O  = (__hip_bfloat16*)(ws + 67108864L);
  auto GAF  = (float*)(ws + 0L);
  auto OUT0 = (__hip_bfloat16*)(ws + 201326592L);
  auto OUT1 = (__hip_bfloat16*)(ws + 67108864L);
  auto QKV  = (__hip_bfloat16*)(ws + 83886080L);
  auto AOb  = (__hip_bfloat16*)(ws + 134217728L);
  auto PROJ = (float*)(ws + 150994944L);
  auto ATT  = (float*)(ws + 184549376L);
  auto WAUG1 = (__hip_bfloat16*)(ws + 201326592L);            // (144,64)
  auto WAUG2 = (__hip_bfloat16*)(ws + 201326592L + 20480L);   // (144,128)
  char* WB  = ws + 218103808L;
  auto WC2   = (__hip_bfloat16*)(WB + 0);        // (64,160) reordered conv2 w
  auto SC2   = (float*)(WB + 20480);             // (64) BN scale
  auto SH2   = (float*)(WB + 20736);             // (64) BN shift
  auto WI0F  = (__hip_bfloat16*)(WB + 49152);    // (512,2048)
  auto WI0R  = (__hip_bfloat16*)(WB + 2146304);
  auto WI1F  = (__hip_bfloat16*)(WB + 4243456);  // (512,256)
  auto WI1R  = (__hip_bfloat16*)(WB + 4505600);
  auto WQKVb = (__hip_bfloat16*)(WB + 4767744);  // (768,256)
  auto WOb   = (__hip_bfloat16*)(WB + 5160960);  // (256,256)

  // --- weight prep ---
  gat_waug_k<<<36, 256, 0, stream>>>(g1W, g1asrc, g1adst, WAUG1, 64);
  gat_waug_k<<<72, 256, 0, stream>>>(g2W, g2asrc, g2adst, WAUG2, 128);
  conv2w_k<<<40, 256, 0, stream>>>(c2w, c2b, bn2g, bn2b, WC2, SC2, SH2);
  cvt_bf16_k<<<4096, 256, 0, stream>>>(l0fWih, WI0F, 1048576);
  cvt_bf16_k<<<4096, 256, 0, stream>>>(l0rWih, WI0R, 1048576);
  cvt_bf16_k<<<512, 256, 0, stream>>>(l1fWih, WI1F, 131072);
  cvt_bf16_k<<<512, 256, 0, stream>>>(l1rWih, WI1R, 131072);
  cvt_bf16_k<<<768, 256, 0, stream>>>(wqkv, WQKVb, 196608);
  cvt_bf16_k<<<256, 256, 0, stream>>>(wo, WOb, 65536);

  // --- pipeline ---
  conv1_k<<<4096, 256, 0, stream>>>(x, c1w, c1b, bn1g, bn1b, C1);
  conv2_mfma_k<<<4096, 256, 0, stream>>>(C1, WC2, SC2, SH2, G0);
  gat_fused_k<64><<<32768, 128, 0, stream>>>(G0, WAUG1, g1adj, n1g, n1b, G1O);
  gat_fused_k<128><<<32768, 128, 0, stream>>>(G1O, WAUG2, g2adj, n2g, n2b, G1O);
  // LSTM layer 0 (dirs serialized on one gate buffer)
  gemm_bt<false><<<dim3(4, 256), 256, 0, stream>>>(G1O, WI0F, GAF, nullptr, 32768, 512, 2048);
  lstm_mfma_k<<<128, 512, 0, stream>>>(GAF, l0fWhh, l0fbih, l0fbhh, OUT0, 0, 0);
  gemm_bt<false><<<dim3(4, 256), 256, 0, stream>>>(G1O, WI0R, GAF, nullptr, 32768, 512, 2048);
  lstm_mfma_k<<<128, 512, 0, stream>>>(GAF, l0rWhh, l0rbih, l0rbhh, OUT0, 1, 128);
  // LSTM layer 1
  gemm_bt<false><<<dim3(4, 256), 256, 0, stream>>>(OUT0, WI1F, GAF, nullptr, 32768, 512, 256);
  lstm_mfma_k<<<128, 512, 0, stream>>>(GAF, l1fWhh, l1fbih, l1fbhh, OUT1, 0, 0);
  gemm_bt<false><<<dim3(4, 256), 256, 0, stream>>>(OUT0, WI1R, GAF, nullptr, 32768, 512, 256);
  lstm_mfma_k<<<128, 512, 0, stream>>>(GAF, l1rWhh, l1rbih, l1rbhh, OUT1, 1, 128);
  // MHA block
  gemm_bt<true><<<dim3(6, 256), 256, 0, stream>>>(OUT1, WQKVb, QKV, bqkv, 32768, 768, 256);
  mha_k<<<1024, 256, 0, stream>>>(QKV, AOb);
  gemm_bt<false><<<dim3(2, 256), 256, 0, stream>>>(AOb, WOb, PROJ, bo, 32768, 256, 256);
  resid_ln_k<<<32768, 256, 0, stream>>>(PROJ, OUT1, ang, anb, ATT);
  pool_k<<<256, 256, 0, stream>>>(ATT, png, pnb, f1w, f1b, f2w, f2b, (float*)d_out);
}

// Round 8
// 1419.867 us; speedup vs baseline: 2.7027x; 1.0201x over previous
//
#include <hip/hip_runtime.h>
#include <hip/hip_bf16.h>
#include <stdint.h>

// ---------------------------------------------------------------------------
// M6_GraphBiLSTM: conv1 -> conv2 -> GAT x2 -> BiLSTM x2 -> MHA -> pool -> FC
// Round 8: gat1+gat2 fused into ONE kernel (R7 profile: gat_fused_k x2
// @203us = 28%; the two layers are independent per n). Layer-1 output h1
// kept bf16 in LDS [16][136] (+8 pad -> layer-2 A-frag reads 2-way/free);
// saves a 134MB global round-trip and one 32768-block launch. Math identical
// (h1 passed through bf16 before too).
// Shapes: B=256, C=16, T=256, TC=128, H=128, HEADS=4, D=32, E=256
// ---------------------------------------------------------------------------

typedef __attribute__((ext_vector_type(8))) short bh8;    // 8 x bf16 (4 VGPR)
typedef __attribute__((ext_vector_type(4))) float f32x4;  // MFMA accumulator

__device__ __forceinline__ float bfu2f(unsigned short u) {
  union { unsigned u; float f; } x; x.u = ((unsigned)u) << 16; return x.f;
}
__device__ __forceinline__ unsigned short f2bfu(float f) {
  __hip_bfloat16 h = __float2bfloat16(f);
  return *reinterpret_cast<unsigned short*>(&h);
}
__device__ __forceinline__ float geluf(float v) {
  return 0.5f * v * (1.f + erff(v * 0.70710678118f));
}
__device__ __forceinline__ float sigmoidf_(float x) { return 1.f / (1.f + __expf(-x)); }
__device__ __forceinline__ float tanh_(float x) {
  x = fminf(fmaxf(x, -30.f), 30.f);
  float e = __expf(2.f * x);
  return (e - 1.f) / (e + 1.f);
}

// async global->LDS, 16B per lane; LDS dest = wave-uniform base + lane*16
__device__ __forceinline__ void g2l16(const void* g, void* l) {
  __builtin_amdgcn_global_load_lds(
      (const __attribute__((address_space(1))) unsigned int*)g,
      (__attribute__((address_space(3))) unsigned int*)l, 16, 0, 0);
}

// ---------------------------------------------------------------------------
// Weight prep
// ---------------------------------------------------------------------------
__global__ __launch_bounds__(256) void cvt_bf16_k(const float* __restrict__ s,
                                                  __hip_bfloat16* __restrict__ d, int n) {
  int i = blockIdx.x * 256 + threadIdx.x;
  if (i < n) d[i] = __float2bfloat16(s[i]);
}

// Augmented GAT weight: waug (144 rows x K) bf16.
__global__ __launch_bounds__(256)
void gat_waug_k(const float* __restrict__ W, const float* __restrict__ asrc,
                const float* __restrict__ adst, __hip_bfloat16* __restrict__ waug,
                int K) {
  int idx = blockIdx.x * 256 + threadIdx.x;
  if (idx >= 144 * K) return;
  const int row = idx / K, k = idx % K;
  float v = 0.f;
  if (row < 128) {
    v = W[k * 128 + row];
  } else if (row < 136) {
    const int h = (row - 128) & 3;
    const float* av = (row < 132) ? asrc : adst;
    for (int d = 0; d < 32; d++) v += W[k * 128 + h * 32 + d] * av[h * 32 + d];
  }
  waug[row * K + k] = __float2bfloat16(v);
}

// conv2 weight reorder: wc2[oc][kt*32+ic] = w2[oc][ic][kt] bf16, + BN fold
__global__ __launch_bounds__(256)
void conv2w_k(const float* __restrict__ w2, const float* __restrict__ b2,
              const float* __restrict__ g2, const float* __restrict__ bb2,
              __hip_bfloat16* __restrict__ wc2, float* __restrict__ sc,
              float* __restrict__ sh) {
  const int tid = blockIdx.x * 256 + threadIdx.x;
  if (tid < 64 * 160) {
    const int oc = tid / 160, k = tid % 160;
    const int kt = k >> 5, ic = k & 31;
    wc2[tid] = __float2bfloat16(w2[oc * 160 + ic * 5 + kt]);
  }
  if (tid < 64) { sc[tid] = g2[tid]; sh[tid] = b2[tid] * g2[tid] + bb2[tid]; }
}

// ---------------------------------------------------------------------------
// conv1 (k=7, pad 3) + BN + GELU.  x:(4096,256) f32 -> c1:(4096,32,256) bf16
// ---------------------------------------------------------------------------
__global__ __launch_bounds__(256)
void conv1_k(const float* __restrict__ x, const float* __restrict__ w,
             const float* __restrict__ b, const float* __restrict__ g,
             const float* __restrict__ bb, __hip_bfloat16* __restrict__ c1) {
  __shared__ float xs[264];
  const int nn = blockIdx.x, t = threadIdx.x;
  xs[3 + t] = x[nn * 256 + t];
  if (t < 3) { xs[t] = 0.f; xs[259 + t] = 0.f; }
  __syncthreads();
  for (int oc = 0; oc < 32; oc++) {
    float acc = 0.f;
#pragma unroll
    for (int k = 0; k < 7; k++) acc += xs[t + k] * w[oc * 7 + k];
    float v = (acc + b[oc]) * g[oc] + bb[oc];
    c1[(nn * 32 + oc) * 256 + t] = __float2bfloat16(geluf(v));
  }
}

// ---------------------------------------------------------------------------
// conv2 via MFMA (R7). Weights in regs, swizzled LDS input, BN+GELU epilogue.
// ---------------------------------------------------------------------------
__global__ __launch_bounds__(256)
void conv2_mfma_k(const __hip_bfloat16* __restrict__ c1,
                  const __hip_bfloat16* __restrict__ wc2,
                  const float* __restrict__ scale, const float* __restrict__ shift,
                  __hip_bfloat16* __restrict__ g0) {
  const int nn = blockIdx.x, tid = threadIdx.x;
  const int lane = tid & 63, wv = tid >> 6;
  const int cl = lane & 15, hi = lane >> 4;
  __shared__ __align__(16) __hip_bfloat16 L[260 * 32];  // [col][ic] swizzled
  __shared__ float sc_s[64], sh_s[64];
  if (tid < 64) {
    const int pcol = (tid >> 4) < 2 ? (tid >> 4) : 256 + (tid >> 4);
    ((unsigned*)L)[pcol * 16 + (tid & 15)] = 0u;
  }
  if (tid >= 64 && tid < 128) { sc_s[tid - 64] = scale[tid - 64]; sh_s[tid - 64] = shift[tid - 64]; }
  {
    const int ic2 = tid & 15, tg = tid >> 4;
    const __hip_bfloat16* r0 = c1 + ((long)nn * 32 + 2 * ic2) * 256 + tg * 16;
    const bh8 v0a = *(const bh8*)(r0);
    const bh8 v0b = *(const bh8*)(r0 + 8);
    const bh8 v1a = *(const bh8*)(r0 + 256);
    const bh8 v1b = *(const bh8*)(r0 + 264);
    const int g = ic2 >> 2;
#pragma unroll
    for (int e = 0; e < 16; e++) {
      const int col = tg * 16 + e + 2;
      const unsigned lo = (unsigned)(unsigned short)((e < 8) ? v0a[e] : v0b[e - 8]);
      const unsigned hh = (unsigned)(unsigned short)((e < 8) ? v1a[e] : v1b[e - 8]);
      const int pos = (g ^ ((col >> 1) & 3)) * 8 + ((2 * ic2) & 7);
      *(unsigned*)((char*)L + col * 64 + pos * 2) = lo | (hh << 16);
    }
  }
  bh8 af[4][5];
#pragma unroll
  for (int mt = 0; mt < 4; mt++)
#pragma unroll
    for (int kt = 0; kt < 5; kt++)
      af[mt][kt] = *(const bh8*)(wc2 + (mt * 16 + cl) * 160 + kt * 32 + hi * 8);
  __syncthreads();
  f32x4 acc[4][2] = {};
#pragma unroll
  for (int nf = 0; nf < 2; nf++) {
    const int to = wv * 32 + nf * 16 + cl;
#pragma unroll
    for (int kt = 0; kt < 5; kt++) {
      const int col = 2 * to + kt;
      const bh8 bf = *(const bh8*)((const char*)L + col * 64 + ((hi ^ ((col >> 1) & 3)) * 8) * 2);
#pragma unroll
      for (int mt = 0; mt < 4; mt++)
        acc[mt][nf] = __builtin_amdgcn_mfma_f32_16x16x32_bf16(af[mt][kt], bf, acc[mt][nf], 0, 0, 0);
    }
  }
  const int b = nn >> 4, c = nn & 15;
#pragma unroll
  for (int nf = 0; nf < 2; nf++) {
    const int to = wv * 32 + nf * 16 + cl;
    __hip_bfloat16* outb = g0 + ((long)(b * 128 + to) * 16 + c) * 64;
#pragma unroll
    for (int mt = 0; mt < 4; mt++) {
      ushort4 pk;
      unsigned short* pp = (unsigned short*)&pk;
#pragma unroll
      for (int r = 0; r < 4; r++) {
        const int oc = mt * 16 + hi * 4 + r;
        pp[r] = f2bfu(geluf(acc[mt][nf][r] * sc_s[oc] + sh_s[oc]));
      }
      *(ushort4*)(outb + mt * 16 + hi * 4) = pk;
    }
  }
}

// ---------------------------------------------------------------------------
// bf16 MFMA GEMM:  C(M,N) = A(M,K) @ B(N,K)^T  (+bias[N]), m97 structure,
// with bijective XCD-aware tile swizzle (m204).
// ---------------------------------------------------------------------------
template <bool OUT_BF16>
__global__ __launch_bounds__(256)
void gemm_bt(const __hip_bfloat16* __restrict__ A, const __hip_bfloat16* __restrict__ Bm,
             void* __restrict__ Cout, const float* __restrict__ bias,
             int M, int N, int K) {
  __shared__ __align__(16) __hip_bfloat16 sA[128 * 32];
  __shared__ __align__(16) __hip_bfloat16 sB[128 * 32];
  const int tid = threadIdx.x;
  const int lane = tid & 63, wv = tid >> 6;
  const int wr = wv >> 1, wc = wv & 1;
  int fid = blockIdx.y * gridDim.x + blockIdx.x;
  {
    const int nwg = gridDim.x * gridDim.y;
    const int q = nwg >> 3, r = nwg & 7;
    const int xcd = fid & 7, off = fid >> 3;
    fid = (xcd < r ? xcd * (q + 1) : r * (q + 1) + (xcd - r) * q) + off;
  }
  const long m0 = (long)(fid / gridDim.x) * 128;
  const long n0 = (long)(fid % gridDim.x) * 128;
  const int sa0 = wv * 128 + lane, sa1 = wv * 128 + 64 + lane;
  const int ra0 = sa0 >> 2, ca0 = sa0 & 3;
  const int ra1 = sa1 >> 2, ca1 = sa1 & 3;
  const __hip_bfloat16* a0 = A + (m0 + ra0) * K + ca0 * 8;
  const __hip_bfloat16* a1 = A + (m0 + ra1) * K + ca1 * 8;
  const __hip_bfloat16* b0 = Bm + (n0 + ra0) * K + ca0 * 8;
  const __hip_bfloat16* b1 = Bm + (n0 + ra1) * K + ca1 * 8;
  char* lA0 = (char*)sA + wv * 2048;
  char* lA1 = (char*)sA + wv * 2048 + 1024;
  char* lB0 = (char*)sB + wv * 2048;
  char* lB1 = (char*)sB + wv * 2048 + 1024;
  f32x4 acc[4][4] = {};
  const int rfA = wr * 64 + (lane & 15);
  const int rfB = wc * 64 + (lane & 15);
  const int kf = (lane >> 4) * 8;
  for (int kt = 0; kt < K; kt += 32) {
    __syncthreads();
    g2l16(a0 + kt, lA0);
    g2l16(a1 + kt, lA1);
    g2l16(b0 + kt, lB0);
    g2l16(b1 + kt, lB1);
    __syncthreads();
    bh8 af[4], bf[4];
#pragma unroll
    for (int m = 0; m < 4; m++) af[m] = *(const bh8*)(sA + (rfA + m * 16) * 32 + kf);
#pragma unroll
    for (int n = 0; n < 4; n++) bf[n] = *(const bh8*)(sB + (rfB + n * 16) * 32 + kf);
#pragma unroll
    for (int m = 0; m < 4; m++)
#pragma unroll
      for (int n = 0; n < 4; n++)
        acc[m][n] = __builtin_amdgcn_mfma_f32_16x16x32_bf16(af[m], bf[n], acc[m][n], 0, 0, 0);
  }
#pragma unroll
  for (int n = 0; n < 4; n++) {
    const long col = n0 + wc * 64 + n * 16 + (lane & 15);
    const float bv = bias ? bias[col] : 0.f;
#pragma unroll
    for (int m = 0; m < 4; m++) {
      const long row0 = m0 + wr * 64 + m * 16 + ((lane >> 4) * 4);
#pragma unroll
      for (int r = 0; r < 4; r++) {
        float v = acc[m][n][r] + bv;
        if (OUT_BF16)
          ((__hip_bfloat16*)Cout)[(row0 + r) * N + col] = __float2bfloat16(v);
        else
          ((float*)Cout)[(row0 + r) * N + col] = v;
      }
    }
  }
}

// ---------------------------------------------------------------------------
// Fused DOUBLE GAT layer (per n of 32768):
//   h1 = LN1(ReLU(attn1(g0 @ WAUG1)))   [kept bf16 in LDS, stride 136]
//   out = LN2(ReLU(attn2(h1 @ WAUG2)))  [written bf16 to global]
// waug1 (144,64), waug2 (144,128). es/ed folded into both projections.
// ---------------------------------------------------------------------------
__global__ __launch_bounds__(128)
void gat12_fused_k(const __hip_bfloat16* __restrict__ hin,
                   const __hip_bfloat16* __restrict__ waug1,
                   const float* __restrict__ adj1, const float* __restrict__ n1g,
                   const float* __restrict__ n1b,
                   const __hip_bfloat16* __restrict__ waug2,
                   const float* __restrict__ adj2, const float* __restrict__ n2g,
                   const float* __restrict__ n2b,
                   __hip_bfloat16* __restrict__ outp) {
  const long n = blockIdx.x;
  const int f = threadIdx.x;          // 0..127, f = head*32 + d
  const int lane = f & 63, wv = f >> 6;
  const int head = f >> 5;
  __shared__ float hs[16][132];                       // projected h / o
  __shared__ __hip_bfloat16 h1b[16][136];             // layer-1 out, bf16
  __shared__ float adj1_s[16][16], adj2_s[16][16];
  __shared__ float es_s[16][4], ed_s[16][4];
  __shared__ float a_s[16][65];                       // conflict-free
  __shared__ float mean_s[16], rs_s[16];
  const int ar = lane & 15, hi = lane >> 4, ak = hi * 8;

  // ================= phase A: layer 1 (K=64) =================
  {
    const __hip_bfloat16* An = hin + n * 16 * 64;
    f32x4 pacc[4] = {};
    f32x4 pe = {};
#pragma unroll
    for (int kt = 0; kt < 64; kt += 32) {
      const bh8 af = *(const bh8*)(An + ar * 64 + kt + ak);
#pragma unroll
      for (int s = 0; s < 4; s++) {
        const bh8 bf = *(const bh8*)(waug1 + (wv * 64 + s * 16 + ar) * 64 + kt + ak);
        pacc[s] = __builtin_amdgcn_mfma_f32_16x16x32_bf16(af, bf, pacc[s], 0, 0, 0);
      }
      if (wv == 0) {
        const bh8 be = *(const bh8*)(waug1 + (128 + ar) * 64 + kt + ak);
        pe = __builtin_amdgcn_mfma_f32_16x16x32_bf16(af, be, pe, 0, 0, 0);
      }
    }
    for (int idx = f; idx < 256; idx += 128) {
      adj1_s[idx >> 4][idx & 15] = adj1[idx];
      adj2_s[idx >> 4][idx & 15] = adj2[idx];
    }
#pragma unroll
    for (int s = 0; s < 4; s++)
#pragma unroll
      for (int r = 0; r < 4; r++)
        hs[hi * 4 + r][wv * 64 + s * 16 + ar] = pacc[s][r];
    if (wv == 0 && ar < 8) {
#pragma unroll
      for (int r = 0; r < 4; r++) {
        const int c = hi * 4 + r;
        if (ar < 4) es_s[c][ar] = pe[r];
        else        ed_s[c][ar - 4] = pe[r];
      }
    }
  }
  __syncthreads();
  if (f < 64) {
    const int i = f >> 2, hd = f & 3;
    float ev[16], mx = -1e30f;
#pragma unroll
    for (int j = 0; j < 16; j++) {
      float e = es_s[i][hd] + ed_s[j][hd];
      e = (e > 0.f ? e : 0.2f * e) + adj1_s[i][j];
      ev[j] = e; mx = fmaxf(mx, e);
    }
    float sm = 0.f;
#pragma unroll
    for (int j = 0; j < 16; j++) { ev[j] = __expf(ev[j] - mx); sm += ev[j]; }
    const float inv = 1.f / sm;
#pragma unroll
    for (int j = 0; j < 16; j++) a_s[i][j * 4 + hd] = ev[j] * inv;
  }
  __syncthreads();
  {
    float hv[16];
#pragma unroll
    for (int c = 0; c < 16; c++) hv[c] = hs[c][f];
    __syncthreads();
    float o[16];
#pragma unroll
    for (int i = 0; i < 16; i++) {
      float acc = 0.f;
#pragma unroll
      for (int j = 0; j < 16; j++) acc += a_s[i][j * 4 + head] * hv[j];
      acc = fmaxf(acc, 0.f);
      o[i] = acc;
      hs[i][f] = acc;
    }
    __syncthreads();
    {
      const int i = f >> 3, g = f & 7;
      float s = 0.f, ss = 0.f;
#pragma unroll
      for (int q = 0; q < 16; q++) {
        const float v = hs[i][g * 16 + q];
        s += v; ss += v * v;
      }
#pragma unroll
      for (int m = 1; m < 8; m <<= 1) { s += __shfl_xor(s, m); ss += __shfl_xor(ss, m); }
      if (g == 0) {
        const float mean = s * (1.f / 128.f);
        const float var = ss * (1.f / 128.f) - mean * mean;
        mean_s[i] = mean;
        rs_s[i] = rsqrtf(var + 1e-5f);
      }
    }
    __syncthreads();
    const float gw = n1g[f], gb = n1b[f];
#pragma unroll
    for (int i = 0; i < 16; i++)
      h1b[i][f] = __float2bfloat16((o[i] - mean_s[i]) * rs_s[i] * gw + gb);
  }
  __syncthreads();

  // ================= phase B: layer 2 (K=128, A from LDS) =================
  {
    f32x4 pacc[4] = {};
    f32x4 pe = {};
#pragma unroll
    for (int kt = 0; kt < 128; kt += 32) {
      const bh8 af = *(const bh8*)(&h1b[ar][kt + ak]);
#pragma unroll
      for (int s = 0; s < 4; s++) {
        const bh8 bf = *(const bh8*)(waug2 + (wv * 64 + s * 16 + ar) * 128 + kt + ak);
        pacc[s] = __builtin_amdgcn_mfma_f32_16x16x32_bf16(af, bf, pacc[s], 0, 0, 0);
      }
      if (wv == 0) {
        const bh8 be = *(const bh8*)(waug2 + (128 + ar) * 128 + kt + ak);
        pe = __builtin_amdgcn_mfma_f32_16x16x32_bf16(af, be, pe, 0, 0, 0);
      }
    }
    __syncthreads();  // all h1b reads done; hs/es/ed free to overwrite
#pragma unroll
    for (int s = 0; s < 4; s++)
#pragma unroll
      for (int r = 0; r < 4; r++)
        hs[hi * 4 + r][wv * 64 + s * 16 + ar] = pacc[s][r];
    if (wv == 0 && ar < 8) {
#pragma unroll
      for (int r = 0; r < 4; r++) {
        const int c = hi * 4 + r;
        if (ar < 4) es_s[c][ar] = pe[r];
        else        ed_s[c][ar - 4] = pe[r];
      }
    }
  }
  __syncthreads();
  if (f < 64) {
    const int i = f >> 2, hd = f & 3;
    float ev[16], mx = -1e30f;
#pragma unroll
    for (int j = 0; j < 16; j++) {
      float e = es_s[i][hd] + ed_s[j][hd];
      e = (e > 0.f ? e : 0.2f * e) + adj2_s[i][j];
      ev[j] = e; mx = fmaxf(mx, e);
    }
    float sm = 0.f;
#pragma unroll
    for (int j = 0; j < 16; j++) { ev[j] = __expf(ev[j] - mx); sm += ev[j]; }
    const float inv = 1.f / sm;
#pragma unroll
    for (int j = 0; j < 16; j++) a_s[i][j * 4 + hd] = ev[j] * inv;
  }
  __syncthreads();
  {
    float hv[16];
#pragma unroll
    for (int c = 0; c < 16; c++) hv[c] = hs[c][f];
    __syncthreads();
    float o[16];
#pragma unroll
    for (int i = 0; i < 16; i++) {
      float acc = 0.f;
#pragma unroll
      for (int j = 0; j < 16; j++) acc += a_s[i][j * 4 + head] * hv[j];
      acc = fmaxf(acc, 0.f);
      o[i] = acc;
      hs[i][f] = acc;
    }
    __syncthreads();
    {
      const int i = f >> 3, g = f & 7;
      float s = 0.f, ss = 0.f;
#pragma unroll
      for (int q = 0; q < 16; q++) {
        const float v = hs[i][g * 16 + q];
        s += v; ss += v * v;
      }
#pragma unroll
      for (int m = 1; m < 8; m <<= 1) { s += __shfl_xor(s, m); ss += __shfl_xor(ss, m); }
      if (g == 0) {
        const float mean = s * (1.f / 128.f);
        const float var = ss * (1.f / 128.f) - mean * mean;
        mean_s[i] = mean;
        rs_s[i] = rsqrtf(var + 1e-5f);
      }
    }
    __syncthreads();
    const float gw = n2g[f], gb = n2b[f];
#pragma unroll
    for (int i = 0; i < 16; i++)
      outp[(n * 16 + i) * 128 + f] = __float2bfloat16((o[i] - mean_s[i]) * rs_s[i] * gw + gb);
  }
}

// ---------------------------------------------------------------------------
// BiLSTM recurrence via MFMA (see R5 notes). 128 blocks, 8 waves, Whh in regs.
// ---------------------------------------------------------------------------
__global__ __launch_bounds__(512)
void lstm_mfma_k(const float* __restrict__ gates, const float* __restrict__ whh,
                 const float* __restrict__ bih, const float* __restrict__ bhh,
                 __hip_bfloat16* __restrict__ outp, const int dir, const int colOff) {
  const int chunk = blockIdx.x;
  const int tid = threadIdx.x;
  const int lane = tid & 63, w = tid >> 6;
  const int cl = lane & 15, hi = lane >> 4;
  __shared__ __align__(16) __hip_bfloat16 h_frag[2048];
  __shared__ float g_lds[2][520];
  for (int idx = tid; idx < 1024; idx += 512) ((unsigned*)h_frag)[idx] = 0u;
  bh8 bfr[4][4];
#pragma unroll
  for (int n = 0; n < 4; n++)
#pragma unroll
    for (int kt = 0; kt < 4; kt++) {
      const float* wp = whh + (w * 64 + n * 16 + cl) * 128 + kt * 32 + hi * 8;
      const float4 lo = *(const float4*)wp;
      const float4 hv = *(const float4*)(wp + 4);
      bh8 r;
      r[0] = (short)f2bfu(lo.x); r[1] = (short)f2bfu(lo.y);
      r[2] = (short)f2bfu(lo.z); r[3] = (short)f2bfu(lo.w);
      r[4] = (short)f2bfu(hv.x); r[5] = (short)f2bfu(hv.y);
      r[6] = (short)f2bfu(hv.z); r[7] = (short)f2bfu(hv.w);
      bfr[n][kt] = r;
    }
  float bs[4];
#pragma unroll
  for (int n = 0; n < 4; n++)
    bs[n] = bih[w * 64 + n * 16 + cl] + bhh[w * 64 + n * 16 + cl];
  const int ub = tid >> 7, uj = tid & 127;
  float c_st = 0.f;
  __syncthreads();
  for (int s = 0; s < 128; s++) {
    const int t = dir ? (127 - s) : s;
    float gin[4][2];
    if (hi == 0) {
#pragma unroll
      for (int n = 0; n < 4; n++)
#pragma unroll
        for (int r = 0; r < 2; r++)
          gin[n][r] = gates[((long)(chunk * 2 + r) * 128 + t) * 512 + w * 64 + n * 16 + cl];
    }
    bh8 af[4];
#pragma unroll
    for (int kt = 0; kt < 4; kt++)
      af[kt] = *(const bh8*)(h_frag + kt * 512 + lane * 8);
    f32x4 acc[4] = {};
#pragma unroll
    for (int n = 0; n < 4; n++)
#pragma unroll
      for (int kt = 0; kt < 4; kt++)
        acc[n] = __builtin_amdgcn_mfma_f32_16x16x32_bf16(af[kt], bfr[n][kt], acc[n], 0, 0, 0);
    if (hi == 0) {
#pragma unroll
      for (int n = 0; n < 4; n++)
#pragma unroll
        for (int r = 0; r < 2; r++)
          g_lds[r][w * 64 + n * 16 + cl] = acc[n][r] + gin[n][r] + bs[n];
    }
    __syncthreads();
    if (tid < 256) {
      const float gi = sigmoidf_(g_lds[ub][uj]);
      const float gf = sigmoidf_(g_lds[ub][uj + 128]);
      const float gg = tanh_(g_lds[ub][uj + 256]);
      const float go = sigmoidf_(g_lds[ub][uj + 384]);
      const float c = gf * c_st + gi * gg;
      c_st = c;
      const float hh = go * tanh_(c);
      h_frag[(uj >> 5) * 512 + ((uj >> 3) & 3) * 128 + ub * 8 + (uj & 7)] =
          __float2bfloat16(hh);
      outp[((long)(chunk * 2 + ub) * 128 + t) * 256 + colOff + uj] = __float2bfloat16(hh);
    }
    __syncthreads();
  }
}

// ---------------------------------------------------------------------------
// MHA attention core: per (b, head) block. qkv bf16 (32768,768) -> ao bf16
// ---------------------------------------------------------------------------
#define DOT8T(Q, O, KV)                                                        \
  (Q[(O) + 0] * bfu2f((unsigned short)(KV)[0]) +                               \
   Q[(O) + 1] * bfu2f((unsigned short)(KV)[1]) +                               \
   Q[(O) + 2] * bfu2f((unsigned short)(KV)[2]) +                               \
   Q[(O) + 3] * bfu2f((unsigned short)(KV)[3]) +                               \
   Q[(O) + 4] * bfu2f((unsigned short)(KV)[4]) +                               \
   Q[(O) + 5] * bfu2f((unsigned short)(KV)[5]) +                               \
   Q[(O) + 6] * bfu2f((unsigned short)(KV)[6]) +                               \
   Q[(O) + 7] * bfu2f((unsigned short)(KV)[7]))

__global__ __launch_bounds__(256)
void mha_k(const __hip_bfloat16* __restrict__ qkv, __hip_bfloat16* __restrict__ ao) {
  const int bh = blockIdx.x;
  const int b = bh >> 2, hd = bh & 3;
  const int tid = threadIdx.x;
  __shared__ __align__(16) __hip_bfloat16 ks[128 * 68];
  __shared__ __align__(16) __hip_bfloat16 vs[128 * 68];
  __shared__ __align__(16) char xreg[33792];
  __shared__ float mx_s[2][128], sm_s[2][128];
  const long base = (long)b * 128 * 768 + hd * 64;
  for (int idx = tid; idx < 3072; idx += 256) {
    const int mm = idx >> 10, cc = idx & 1023;
    const int t = cc >> 3, c8 = cc & 7;
    const bh8 val = *(const bh8*)(qkv + base + (long)t * 768 + mm * 256 + c8 * 8);
    __hip_bfloat16* dst = (mm == 0) ? (__hip_bfloat16*)xreg : (mm == 1 ? ks : vs);
    *(bh8*)(dst + t * 68 + c8 * 8) = val;
  }
  __syncthreads();
  const int i = tid & 127;
  const int jh = tid >> 7;
  float qf[64];
#pragma unroll
  for (int kk = 0; kk < 8; kk++) {
    const bh8 v8 = *(const bh8*)((const __hip_bfloat16*)xreg + i * 68 + kk * 8);
#pragma unroll
    for (int e = 0; e < 8; e++) qf[kk * 8 + e] = bfu2f((unsigned short)v8[e]);
  }
  float s[64];
#pragma unroll
  for (int jo = 0; jo < 64; jo++) {
    const int j = jh * 64 + jo;
    float acc = 0.f;
#pragma unroll
    for (int kk = 0; kk < 8; kk++) {
      const bh8 kv = *(const bh8*)(ks + j * 68 + kk * 8);
      acc += DOT8T(qf, kk * 8, kv);
    }
    s[jo] = acc * 0.125f;
  }
  float mx = -1e30f;
#pragma unroll
  for (int jo = 0; jo < 64; jo++) mx = fmaxf(mx, s[jo]);
  mx_s[jh][i] = mx;
  __syncthreads();
  const float m = fmaxf(mx_s[0][i], mx_s[1][i]);
  float sum = 0.f;
#pragma unroll
  for (int jo = 0; jo < 64; jo++) { s[jo] = __expf(s[jo] - m); sum += s[jo]; }
  sm_s[jh][i] = sum;
  __syncthreads();
  const float inv = 1.f / (sm_s[0][i] + sm_s[1][i]);
  __hip_bfloat16* P = (__hip_bfloat16*)xreg;
#pragma unroll
  for (int jo = 0; jo < 64; jo += 2) {
    const unsigned u = (unsigned)f2bfu(s[jo] * inv) | ((unsigned)f2bfu(s[jo + 1] * inv) << 16);
    *(unsigned*)(P + i * 132 + jh * 64 + jo) = u;
  }
  __syncthreads();
  const int dh = jh;
  float acc[32];
#pragma unroll
  for (int e = 0; e < 32; e++) acc[e] = 0.f;
  for (int j = 0; j < 128; j++) {
    const float p = bfu2f(*(const unsigned short*)(P + i * 132 + j));
#pragma unroll
    for (int kk = 0; kk < 4; kk++) {
      const bh8 vv = *(const bh8*)(vs + j * 68 + dh * 32 + kk * 8);
      acc[kk * 8 + 0] += p * bfu2f((unsigned short)vv[0]);
      acc[kk * 8 + 1] += p * bfu2f((unsigned short)vv[1]);
      acc[kk * 8 + 2] += p * bfu2f((unsigned short)vv[2]);
      acc[kk * 8 + 3] += p * bfu2f((unsigned short)vv[3]);
      acc[kk * 8 + 4] += p * bfu2f((unsigned short)vv[4]);
      acc[kk * 8 + 5] += p * bfu2f((unsigned short)vv[5]);
      acc[kk * 8 + 6] += p * bfu2f((unsigned short)vv[6]);
      acc[kk * 8 + 7] += p * bfu2f((unsigned short)vv[7]);
    }
  }
  const long ob = ((long)b * 128 + i) * 256 + hd * 64 + dh * 32;
#pragma unroll
  for (int kk = 0; kk < 16; kk++) {
    const unsigned u = (unsigned)f2bfu(acc[2 * kk]) | ((unsigned)f2bfu(acc[2 * kk + 1]) << 16);
    *(unsigned*)(ao + ob + kk * 2) = u;
  }
}

// ---------------------------------------------------------------------------
// residual + LayerNorm(256)
// ---------------------------------------------------------------------------
__global__ __launch_bounds__(256)
void resid_ln_k(const float* __restrict__ proj, const __hip_bfloat16* __restrict__ o,
                const float* __restrict__ g, const float* __restrict__ bb,
                float* __restrict__ att) {
  const long m = blockIdx.x;
  const int t = threadIdx.x;
  const float v = proj[m * 256 + t] + __bfloat162float(o[m * 256 + t]);
  float sv = v, ssv = v * v;
#pragma unroll
  for (int mm = 1; mm < 64; mm <<= 1) { sv += __shfl_xor(sv, mm); ssv += __shfl_xor(ssv, mm); }
  __shared__ float red[4][2];
  const int lane = t & 63, wv = t >> 6;
  if (lane == 0) { red[wv][0] = sv; red[wv][1] = ssv; }
  __syncthreads();
  const float S = red[0][0] + red[1][0] + red[2][0] + red[3][0];
  const float SS = red[0][1] + red[1][1] + red[2][1] + red[3][1];
  const float mu = S * (1.f / 256.f);
  const float rr = rsqrtf(SS * (1.f / 256.f) - mu * mu + 1e-5f);
  att[m * 256 + t] = (v - mu) * rr * g[t] + bb[t];
}

// ---------------------------------------------------------------------------
// pooling (mean+max over t) -> LN(512) -> fc1+relu -> fc2 -> d_out[b]
// ---------------------------------------------------------------------------
__global__ __launch_bounds__(256)
void pool_k(const float* __restrict__ att, const float* __restrict__ png,
            const float* __restrict__ pnb, const float* __restrict__ f1w,
            const float* __restrict__ f1b, const float* __restrict__ f2w,
            const float* __restrict__ f2b, float* __restrict__ outp) {
  const int b = blockIdx.x, e = threadIdx.x;
  float sum = 0.f, mx = -1e30f;
  for (int t = 0; t < 128; t++) {
    const float v = att[((long)b * 128 + t) * 256 + e];
    sum += v; mx = fmaxf(mx, v);
  }
  const float a0 = sum * (1.f / 128.f), a1 = mx;
  float sv = a0 + a1, ssv = a0 * a0 + a1 * a1;
#pragma unroll
  for (int mm = 1; mm < 64; mm <<= 1) { sv += __shfl_xor(sv, mm); ssv += __shfl_xor(ssv, mm); }
  __shared__ float red[4][2];
  __shared__ float y[512];
  __shared__ float z[128];
  const int lane = e & 63, wv = e >> 6;
  if (lane == 0) { red[wv][0] = sv; red[wv][1] = ssv; }
  __syncthreads();
  const float S = red[0][0] + red[1][0] + red[2][0] + red[3][0];
  const float SS = red[0][1] + red[1][1] + red[2][1] + red[3][1];
  const float mu = S * (1.f / 512.f);
  const float rr = rsqrtf(SS * (1.f / 512.f) - mu * mu + 1e-5f);
  y[e] = (a0 - mu) * rr * png[e] + pnb[e];
  y[256 + e] = (a1 - mu) * rr * png[256 + e] + pnb[256 + e];
  __syncthreads();
  if (e < 128) {
    float a = f1b[e];
    for (int k = 0; k < 512; k++) a += y[k] * f1w[e * 512 + k];
    z[e] = fmaxf(a, 0.f);
  }
  __syncthreads();
  if (e < 64) {
    float p = z[e] * f2w[e] + z[e + 64] * f2w[e + 64];
#pragma unroll
    for (int mm = 1; mm < 64; mm <<= 1) p += __shfl_xor(p, mm);
    if (e == 0) outp[b] = p + f2b[0];
  }
}

// ---------------------------------------------------------------------------
// Host orchestration
// ---------------------------------------------------------------------------
extern "C" void kernel_launch(void* const* d_in, const int* in_sizes, int n_in,
                              void* d_out, int out_size, void* d_ws, size_t ws_size,
                              hipStream_t stream) {
  (void)in_sizes; (void)n_in; (void)out_size; (void)ws_size;
  const float* x      = (const float*)d_in[0];
  const float* c1w    = (const float*)d_in[1];
  const float* c1b    = (const float*)d_in[2];
  const float* bn1g   = (const float*)d_in[3];
  const float* bn1b   = (const float*)d_in[4];
  const float* c2w    = (const float*)d_in[5];
  const float* c2b    = (const float*)d_in[6];
  const float* bn2g   = (const float*)d_in[7];
  const float* bn2b   = (const float*)d_in[8];
  const float* g1W    = (const float*)d_in[9];
  const float* g1asrc = (const float*)d_in[10];
  const float* g1adst = (const float*)d_in[11];
  const float* g1adj  = (const float*)d_in[12];
  const float* n1g    = (const float*)d_in[13];
  const float* n1b    = (const float*)d_in[14];
  const float* g2W    = (const float*)d_in[15];
  const float* g2asrc = (const float*)d_in[16];
  const float* g2adst = (const float*)d_in[17];
  const float* g2adj  = (const float*)d_in[18];
  const float* n2g    = (const float*)d_in[19];
  const float* n2b    = (const float*)d_in[20];
  const float* l0fWih = (const float*)d_in[21];
  const float* l0fWhh = (const float*)d_in[22];
  const float* l0fbih = (const float*)d_in[23];
  const float* l0fbhh = (const float*)d_in[24];
  const float* l0rWih = (const float*)d_in[25];
  const float* l0rWhh = (const float*)d_in[26];
  const float* l0rbih = (const float*)d_in[27];
  const float* l0rbhh = (const float*)d_in[28];
  const float* l1fWih = (const float*)d_in[29];
  const float* l1fWhh = (const float*)d_in[30];
  const float* l1fbih = (const float*)d_in[31];
  const float* l1fbhh = (const float*)d_in[32];
  const float* l1rWih = (const float*)d_in[33];
  const float* l1rWhh = (const float*)d_in[34];
  const float* l1rbih = (const float*)d_in[35];
  const float* l1rbhh = (const float*)d_in[36];
  const float* wqkv   = (const float*)d_in[37];
  const float* bqkv   = (const float*)d_in[38];
  const float* wo     = (const float*)d_in[39];
  const float* bo     = (const float*)d_in[40];
  const float* ang    = (const float*)d_in[41];
  const float* anb    = (const float*)d_in[42];
  const float* png    = (const float*)d_in[43];
  const float* pnb    = (const float*)d_in[44];
  const float* f1w    = (const float*)d_in[45];
  const float* f1b    = (const float*)d_in[46];
  const float* f2w    = (const float*)d_in[47];
  const float* f2b    = (const float*)d_in[48];

  char* ws = (char*)d_ws;
  // Buffer overlay plan (total 223,395,840 B; lifetimes verified per stage):
  //  [0       , 67.1MB ) G0   (conv2 out) ........ then GAF (lstm gates f32)
  //  [67.1MB  , 134.2MB) C1   (conv1 out) ........ then low half of G1O,
  //                                               then OUT1 + QKV
  //  [67.1MB  , 201.3MB) G1O  (GAT out) ... then AOb, PROJ, ATT
  //  [201.3MB , 218.1MB) WAUG1/2 (during conv+GAT) then OUT0 (lstm0 out)
  //  [218.1MB , 223.4MB) bf16 weights (persistent; wc2/sc/sh in first 49KB)
  auto G0   = (__hip_bfloat16*)(ws + 0L);
  auto C1   = (__hip_bfloat16*)(ws + 67108864L);
  auto G1O  = (__hip_bfloat16*)(ws + 67108864L);
  auto GAF  = (float*)(ws + 0L);
  auto OUT0 = (__hip_bfloat16*)(ws + 201326592L);
  auto OUT1 = (__hip_bfloat16*)(ws + 67108864L);
  auto QKV  = (__hip_bfloat16*)(ws + 83886080L);
  auto AOb  = (__hip_bfloat16*)(ws + 134217728L);
  auto PROJ = (float*)(ws + 150994944L);
  auto ATT  = (float*)(ws + 184549376L);
  auto WAUG1 = (__hip_bfloat16*)(ws + 201326592L);            // (144,64)
  auto WAUG2 = (__hip_bfloat16*)(ws + 201326592L + 20480L);   // (144,128)
  char* WB  = ws + 218103808L;
  auto WC2   = (__hip_bfloat16*)(WB + 0);        // (64,160) reordered conv2 w
  auto SC2   = (float*)(WB + 20480);             // (64) BN scale
  auto SH2   = (float*)(WB + 20736);             // (64) BN shift
  auto WI0F  = (__hip_bfloat16*)(WB + 49152);    // (512,2048)
  auto WI0R  = (__hip_bfloat16*)(WB + 2146304);
  auto WI1F  = (__hip_bfloat16*)(WB + 4243456);  // (512,256)
  auto WI1R  = (__hip_bfloat16*)(WB + 4505600);
  auto WQKVb = (__hip_bfloat16*)(WB + 4767744);  // (768,256)
  auto WOb   = (__hip_bfloat16*)(WB + 5160960);  // (256,256)

  // --- weight prep ---
  gat_waug_k<<<36, 256, 0, stream>>>(g1W, g1asrc, g1adst, WAUG1, 64);
  gat_waug_k<<<72, 256, 0, stream>>>(g2W, g2asrc, g2adst, WAUG2, 128);
  conv2w_k<<<40, 256, 0, stream>>>(c2w, c2b, bn2g, bn2b, WC2, SC2, SH2);
  cvt_bf16_k<<<4096, 256, 0, stream>>>(l0fWih, WI0F, 1048576);
  cvt_bf16_k<<<4096, 256, 0, stream>>>(l0rWih, WI0R, 1048576);
  cvt_bf16_k<<<512, 256, 0, stream>>>(l1fWih, WI1F, 131072);
  cvt_bf16_k<<<512, 256, 0, stream>>>(l1rWih, WI1R, 131072);
  cvt_bf16_k<<<768, 256, 0, stream>>>(wqkv, WQKVb, 196608);
  cvt_bf16_k<<<256, 256, 0, stream>>>(wo, WOb, 65536);

  // --- pipeline ---
  conv1_k<<<4096, 256, 0, stream>>>(x, c1w, c1b, bn1g, bn1b, C1);
  conv2_mfma_k<<<4096, 256, 0, stream>>>(C1, WC2, SC2, SH2, G0);
  gat12_fused_k<<<32768, 128, 0, stream>>>(G0, WAUG1, g1adj, n1g, n1b,
                                           WAUG2, g2adj, n2g, n2b, G1O);
  // LSTM layer 0 (dirs serialized on one gate buffer)
  gemm_bt<false><<<dim3(4, 256), 256, 0, stream>>>(G1O, WI0F, GAF, nullptr, 32768, 512, 2048);
  lstm_mfma_k<<<128, 512, 0, stream>>>(GAF, l0fWhh, l0fbih, l0fbhh, OUT0, 0, 0);
  gemm_bt<false><<<dim3(4, 256), 256, 0, stream>>>(G1O, WI0R, GAF, nullptr, 32768, 512, 2048);
  lstm_mfma_k<<<128, 512, 0, stream>>>(GAF, l0rWhh, l0rbih, l0rbhh, OUT0, 1, 128);
  // LSTM layer 1
  gemm_bt<false><<<dim3(4, 256), 256, 0, stream>>>(OUT0, WI1F, GAF, nullptr, 32768, 512, 256);
  lstm_mfma_k<<<128, 512, 0, stream>>>(GAF, l1fWhh, l1fbih, l1fbhh, OUT1, 0, 0);
  gemm_bt<false><<<dim3(4, 256), 256, 0, stream>>>(OUT0, WI1R, GAF, nullptr, 32768, 512, 256);
  lstm_mfma_k<<<128, 512, 0, stream>>>(GAF, l1rWhh, l1rbih, l1rbhh, OUT1, 1, 128);
  // MHA block
  gemm_bt<true><<<dim3(6, 256), 256, 0, stream>>>(OUT1, WQKVb, QKV, bqkv, 32768, 768, 256);
  mha_k<<<1024, 256, 0, stream>>>(QKV, AOb);
  gemm_bt<false><<<dim3(2, 256), 256, 0, stream>>>(AOb, WOb, PROJ, bo, 32768, 256, 256);
  resid_ln_k<<<32768, 256, 0, stream>>>(PROJ, OUT1, ang, anb, ATT);
  pool_k<<<256, 256, 0, stream>>>(ATT, png, pnb, f1w, f1b, f2w, f2b, (float*)d_out);
}